// Round 1
// baseline (751.112 us; speedup 1.0000x reference)
//
#include <hip/hip_runtime.h>
#include <hip/hip_bf16.h>

// Problem constants
constexpr int B = 2, S = 2048, D = 1024;
constexpr int H = 16, KVH = 4, HD = 64;
constexpr int WINDOW = 64;
constexpr int N_REP = H / KVH;        // 4
constexpr int BS = B * S;             // 4096 rows

// ---------------------------------------------------------------------------
// Tiled fp32 GEMM: C[M,N] = A[M,K] * W[K,N], all row-major.
// 64x64 output tile per block, 256 threads, 4x4 accumulators per thread.
// M % 64 == 0, N % 64 == 0, K % 16 == 0 assumed (true for all our shapes).
// ---------------------------------------------------------------------------
#define GT 64
#define GKT 16

__global__ __launch_bounds__(256) void gemm_kernel(
    const float* __restrict__ A, const float* __restrict__ W,
    float* __restrict__ C, int M, int N, int K) {
  __shared__ float As[GKT][GT + 4];   // [k][m], pad to 68 floats: breaks 16-way write conflict
  __shared__ float Bs[GKT][GT];       // [k][n]

  const int tid = threadIdx.x;
  const int tx = tid % 16;            // col group
  const int ty = tid / 16;            // row group
  const int row0 = blockIdx.y * GT;
  const int col0 = blockIdx.x * GT;

  float acc[4][4] = {};

  for (int k0 = 0; k0 < K; k0 += GKT) {
    // Load A tile (64 rows x 16 k), coalesced over k within a row.
    {
      const int kk = tid % 16;
      const int r0 = tid / 16;        // 0..15
      #pragma unroll
      for (int rr = 0; rr < 4; ++rr) {
        int r = r0 + rr * 16;
        As[kk][r] = A[(size_t)(row0 + r) * K + k0 + kk];
      }
    }
    // Load W tile (16 k x 64 n), coalesced over n.
    {
      const int n = tid % 64;
      const int kk0 = tid / 64;       // 0..3
      #pragma unroll
      for (int kq = 0; kq < 4; ++kq) {
        int kk = kk0 + kq * 4;
        Bs[kk][n] = W[(size_t)(k0 + kk) * N + col0 + n];
      }
    }
    __syncthreads();

    #pragma unroll
    for (int kk = 0; kk < GKT; ++kk) {
      float4 a4 = *(const float4*)&As[kk][ty * 4];
      float4 b4 = *(const float4*)&Bs[kk][tx * 4];
      float av[4] = {a4.x, a4.y, a4.z, a4.w};
      float bv[4] = {b4.x, b4.y, b4.z, b4.w};
      #pragma unroll
      for (int i = 0; i < 4; ++i)
        #pragma unroll
        for (int j = 0; j < 4; ++j)
          acc[i][j] += av[i] * bv[j];
    }
    __syncthreads();
  }

  #pragma unroll
  for (int i = 0; i < 4; ++i) {
    #pragma unroll
    for (int j = 0; j < 4; ++j) {
      C[(size_t)(row0 + ty * 4 + i) * N + col0 + tx * 4 + j] = acc[i][j];
    }
  }
}

// ---------------------------------------------------------------------------
// RoPE (interleaved pairs): t layout [B, S, NH, HD]; pair f uses elements
// (2f, 2f+1); cos/sin are [S, HD/2].
// ---------------------------------------------------------------------------
__global__ void rope_kernel(float* __restrict__ t,
                            const float* __restrict__ cs,
                            const float* __restrict__ sn, int nheads, int total_pairs) {
  int idx = blockIdx.x * blockDim.x + threadIdx.x;
  if (idx >= total_pairs) return;
  int f = idx % (HD / 2);
  int rest = idx / (HD / 2);          // (b*S + s)*nheads + nh
  int s = (rest / nheads) % S;
  float c = cs[s * (HD / 2) + f];
  float si = sn[s * (HD / 2) + f];
  float a = t[2 * idx];
  float b = t[2 * idx + 1];
  t[2 * idx] = a * c - b * si;
  t[2 * idx + 1] = a * si + b * c;
}

// ---------------------------------------------------------------------------
// Sliding-window attention, one 64-lane wave per (b, i, h); lane = head dim.
// q: [B,S,H,HD]  k,v: [B,S,KVH,HD]  o: [B,S,H,HD]
// ---------------------------------------------------------------------------
__global__ __launch_bounds__(256) void attn_kernel(
    const float* __restrict__ q, const float* __restrict__ k,
    const float* __restrict__ v, float* __restrict__ o) {
  const int wave = (blockIdx.x * blockDim.x + threadIdx.x) >> 6;
  const int lane = threadIdx.x & 63;
  const int h = wave % H;
  const int tmp = wave / H;
  const int i = tmp % S;
  const int b = tmp / S;
  const int kvh = h / N_REP;

  const float qd = q[(size_t)((b * S + i) * H + h) * HD + lane];

  float m = -1e30f, l = 0.f, acc = 0.f;
  const int j0 = (i - WINDOW > 0) ? (i - WINDOW) : 0;

  for (int j = j0; j <= i; ++j) {
    const size_t kvbase = (size_t)((b * S + j) * KVH + kvh) * HD + lane;
    float p = qd * k[kvbase];
    #pragma unroll
    for (int off = 32; off > 0; off >>= 1) p += __shfl_xor(p, off);
    const float score = p * 0.125f;   // 1/sqrt(64)
    const float mn = fmaxf(m, score);
    const float alpha = __expf(m - mn);
    const float pe = __expf(score - mn);
    l = l * alpha + pe;
    acc = acc * alpha + pe * v[kvbase];
    m = mn;
  }
  o[(size_t)((b * S + i) * H + h) * HD + lane] = acc / l;
}

// ---------------------------------------------------------------------------
extern "C" void kernel_launch(void* const* d_in, const int* in_sizes, int n_in,
                              void* d_out, int out_size, void* d_ws, size_t ws_size,
                              hipStream_t stream) {
  const float* x  = (const float*)d_in[0];
  const float* fc = (const float*)d_in[1];
  const float* fs = (const float*)d_in[2];
  const float* wq = (const float*)d_in[3];
  const float* wk = (const float*)d_in[4];
  const float* wv = (const float*)d_in[5];
  const float* wo = (const float*)d_in[6];
  float* out = (float*)d_out;

  // Workspace layout (floats): q | k | v | attn_out
  float* q  = (float*)d_ws;                       // BS * H*HD   = 4M floats
  float* kk = q  + (size_t)BS * H * HD;           // BS * KVH*HD = 1M floats
  float* vv = kk + (size_t)BS * KVH * HD;         // 1M floats
  float* ao = vv + (size_t)BS * KVH * HD;         // 4M floats

  // QKV projections
  gemm_kernel<<<dim3((H * HD) / GT, BS / GT), 256, 0, stream>>>(x, wq, q, BS, H * HD, D);
  gemm_kernel<<<dim3((KVH * HD) / GT, BS / GT), 256, 0, stream>>>(x, wk, kk, BS, KVH * HD, D);
  gemm_kernel<<<dim3((KVH * HD) / GT, BS / GT), 256, 0, stream>>>(x, wv, vv, BS, KVH * HD, D);

  // RoPE
  {
    int qpairs = BS * H * (HD / 2);
    int kpairs = BS * KVH * (HD / 2);
    rope_kernel<<<(qpairs + 255) / 256, 256, 0, stream>>>(q, fc, fs, H, qpairs);
    rope_kernel<<<(kpairs + 255) / 256, 256, 0, stream>>>(kk, fc, fs, KVH, kpairs);
  }

  // Attention: one wave per (b,i,h) -> B*S*H waves, 4 waves per 256-thread block
  attn_kernel<<<(B * S * H) / 4, 256, 0, stream>>>(q, kk, vv, ao);

  // Output projection
  gemm_kernel<<<dim3(D / GT, BS / GT), 256, 0, stream>>>(ao, wo, out, BS, D, H * HD);
}

// Round 2
// 347.800 us; speedup vs baseline: 2.1596x; 2.1596x over previous
//
#include <hip/hip_runtime.h>
#include <hip/hip_bf16.h>

constexpr int B = 2, S = 2048, D = 1024;
constexpr int H = 16, KVH = 4, HD = 64;
constexpr int BS = B * S;                 // 4096
constexpr int QS = H * HD + 2 * KVH * HD; // 1536 qkv row stride
constexpr int KOFF = H * HD;              // 1024
constexpr int VOFF = H * HD + KVH * HD;   // 1280

typedef __attribute__((ext_vector_type(8))) short short8;
typedef __attribute__((ext_vector_type(4))) float floatx4;

static __device__ __forceinline__ unsigned short f2bf(float f) {
  union { float f; unsigned u; } c{f};
  unsigned r = (c.u + 0x7FFFu + ((c.u >> 16) & 1u)) >> 16;
  return (unsigned short)r;
}

// ---------------------------------------------------------------------------
// x fp32 -> bf16 (1M threads, 4 elems each)
// ---------------------------------------------------------------------------
__global__ void cast_x_kernel(const float* __restrict__ x, unsigned short* __restrict__ xb) {
  int t = blockIdx.x * blockDim.x + threadIdx.x;
  float4 v = ((const float4*)x)[t];
  ushort4 o;
  o.x = f2bf(v.x); o.y = f2bf(v.y); o.z = f2bf(v.z); o.w = f2bf(v.w);
  ((ushort4*)xb)[t] = o;
}

// ---------------------------------------------------------------------------
// w fp32 [K=1024, N] row-major -> wT bf16 [N, 1024] at row offset dstOff
// block (32,8), grid (N/32, 32)
// ---------------------------------------------------------------------------
__global__ void transpose_cast_kernel(const float* __restrict__ src,
                                      unsigned short* __restrict__ dst,
                                      int N, int dstOff) {
  __shared__ float t[32][33];
  int n0 = blockIdx.x * 32, k0 = blockIdx.y * 32;
  int tx = threadIdx.x, ty = threadIdx.y;
#pragma unroll
  for (int r = 0; r < 4; ++r)
    t[ty + r * 8][tx] = src[(size_t)(k0 + ty + r * 8) * N + n0 + tx];
  __syncthreads();
#pragma unroll
  for (int r = 0; r < 4; ++r)
    dst[(size_t)(dstOff + n0 + ty + r * 8) * D + k0 + tx] = f2bf(t[tx][ty + r * 8]);
}

// ---------------------------------------------------------------------------
// bf16 MFMA GEMM: C[M,N] fp32 = A[M,K] * Bt[N,K]^T   (Bt is B transposed)
// 128x128 tile, BK=32, 256 threads = 4 waves (2x2 of 64x64), 16x16x32 MFMA.
// LDS tiles XOR-swizzled per row to break frag-read bank conflicts.
// ---------------------------------------------------------------------------
__global__ __launch_bounds__(256) void gemm_bt_kernel(
    const unsigned short* __restrict__ A, const unsigned short* __restrict__ Bt,
    float* __restrict__ C, int N, int K) {
  __shared__ unsigned short As[128 * 32];
  __shared__ unsigned short Bs[128 * 32];
  const int tid = threadIdx.x;
  const int lane = tid & 63, wvid = tid >> 6;
  const int wy = wvid >> 1, wx = wvid & 1;
  const int quad = lane >> 4, lrow = lane & 15;
  const size_t row0 = (size_t)blockIdx.y * 128;
  const size_t col0 = (size_t)blockIdx.x * 128;

  floatx4 zero4 = {0.f, 0.f, 0.f, 0.f};
  floatx4 acc[4][4];
#pragma unroll
  for (int i = 0; i < 4; ++i)
#pragma unroll
    for (int j = 0; j < 4; ++j) acc[i][j] = zero4;

  const int r1 = tid >> 2, cc1 = tid & 3;   // staging: chunk (row, 16B-chunk)
  const int r2 = r1 + 64;

  for (int k0 = 0; k0 < K; k0 += 32) {
    uint4 a1 = *(const uint4*)&A[(row0 + r1) * K + k0 + cc1 * 8];
    uint4 a2 = *(const uint4*)&A[(row0 + r2) * K + k0 + cc1 * 8];
    uint4 b1 = *(const uint4*)&Bt[(col0 + r1) * K + k0 + cc1 * 8];
    uint4 b2 = *(const uint4*)&Bt[(col0 + r2) * K + k0 + cc1 * 8];
    __syncthreads();
    *(uint4*)&As[r1 * 32 + ((cc1 ^ (r1 & 3)) * 8)] = a1;
    *(uint4*)&As[r2 * 32 + ((cc1 ^ (r2 & 3)) * 8)] = a2;
    *(uint4*)&Bs[r1 * 32 + ((cc1 ^ (r1 & 3)) * 8)] = b1;
    *(uint4*)&Bs[r2 * 32 + ((cc1 ^ (r2 & 3)) * 8)] = b2;
    __syncthreads();

    short8 af[4], bg[4];
#pragma unroll
    for (int mi = 0; mi < 4; ++mi) {
      int m = wy * 64 + mi * 16 + lrow;
      af[mi] = *(const short8*)&As[m * 32 + ((quad ^ (m & 3)) * 8)];
    }
#pragma unroll
    for (int ni = 0; ni < 4; ++ni) {
      int n = wx * 64 + ni * 16 + lrow;
      bg[ni] = *(const short8*)&Bs[n * 32 + ((quad ^ (n & 3)) * 8)];
    }
#pragma unroll
    for (int mi = 0; mi < 4; ++mi)
#pragma unroll
      for (int ni = 0; ni < 4; ++ni)
        acc[mi][ni] = __builtin_amdgcn_mfma_f32_16x16x32_bf16(af[mi], bg[ni], acc[mi][ni], 0, 0, 0);
  }

  // epilogue: C/D layout col=lane&15, row=quad*4+reg
#pragma unroll
  for (int mi = 0; mi < 4; ++mi) {
#pragma unroll
    for (int ni = 0; ni < 4; ++ni) {
      size_t col = col0 + wx * 64 + ni * 16 + lrow;
      size_t rowb = row0 + wy * 64 + mi * 16 + quad * 4;
#pragma unroll
      for (int r = 0; r < 4; ++r)
        C[(rowb + r) * N + col] = acc[mi][ni][r];
    }
  }
}

// ---------------------------------------------------------------------------
// RoPE (interleaved pairs) in-place on qkv fp32 [BS, 1536].
// ---------------------------------------------------------------------------
__global__ void rope_kernel(float* __restrict__ qkv, const float* __restrict__ cs,
                            const float* __restrict__ sn, int nheads, int col0, int npairs) {
  int idx = blockIdx.x * blockDim.x + threadIdx.x;
  if (idx >= npairs) return;
  int f = idx & 31;
  int rest = idx >> 5;
  int nh = rest % nheads;
  int bs = rest / nheads;
  int s = bs & (S - 1);
  float c = cs[s * 32 + f], si = sn[s * 32 + f];
  float* p = qkv + (size_t)bs * QS + col0 + nh * HD + 2 * f;
  float a = p[0], b = p[1];
  p[0] = a * c - b * si;
  p[1] = a * si + b * c;
}

// ---------------------------------------------------------------------------
// Fused sliding-window attention. One wave per (b,i,h).
// Phase 1 (lane = window slot): scores + softmax; 18 shuffles total.
// Phase 2 (lane = head-dim d): PV with coalesced v loads, p via LDS float4
// broadcast. Out-of-window slots carry p=0, v index clamped (no OOB).
// ---------------------------------------------------------------------------
__global__ __launch_bounds__(256) void attn_kernel(const float* __restrict__ qkv,
                                                   unsigned short* __restrict__ ao) {
  __shared__ float plds[4][72];
  const int tid = threadIdx.x;
  const int w = tid >> 6, lane = tid & 63;
  const int wg = blockIdx.x * 4 + w;        // (b*S + i)*H + h
  const int h = wg & (H - 1);
  const int bs = wg >> 4;
  const int i = bs & (S - 1);
  const int kvh = h >> 2;
  const float* qrow = qkv + (size_t)bs * QS + h * HD;
  const size_t batchbase = (size_t)(bs - i) * QS;   // b*S*QS
  const float* kbase = qkv + batchbase + KOFF + kvh * HD;
  const float* vbase = qkv + batchbase + VOFF + kvh * HD;

  // main score: j = i - 63 + lane (lane 63 = diagonal, always valid)
  int jm = i - 63 + lane;
  int jmc = jm < 0 ? 0 : jm;
  const float* krow = kbase + (size_t)jmc * QS;
  float acc = 0.f;
#pragma unroll
  for (int c = 0; c < 16; ++c) {
    float4 qc = ((const float4*)qrow)[c];
    float4 kc = ((const float4*)krow)[c];
    acc += qc.x * kc.x + qc.y * kc.y + qc.z * kc.z + qc.w * kc.w;
  }
  float s_main = jm >= 0 ? acc * 0.125f : -1e30f;

  // extra score j = i - 64, computed cooperatively (lane = d)
  int je = i - 64;
  int jec = je < 0 ? 0 : je;
  float pr = qrow[lane] * kbase[(size_t)jec * QS + lane];
#pragma unroll
  for (int off = 32; off > 0; off >>= 1) pr += __shfl_xor(pr, off);
  float s_extra = je >= 0 ? pr * 0.125f : -1e30f;

  // softmax over 65 slots
  float m = s_main;
#pragma unroll
  for (int off = 32; off > 0; off >>= 1) m = fmaxf(m, __shfl_xor(m, off));
  m = fmaxf(m, s_extra);
  float e_main = __expf(s_main - m);
  float e_extra = __expf(s_extra - m);
  float lsum = e_main;
#pragma unroll
  for (int off = 32; off > 0; off >>= 1) lsum += __shfl_xor(lsum, off);
  lsum += e_extra;
  float rinv = 1.f / lsum;

  plds[w][lane + 1] = e_main * rinv;                // slots 1..64
  if (lane == 0) plds[w][0] = e_extra * rinv;       // slot 0 (j = i-64)
  if (lane >= 61) plds[w][lane + 4] = 0.f;          // zero slots 65..67
  __syncthreads();

  // PV: lane = d
  float o = 0.f;
  const float* vcol = vbase + lane;
  const float4* p4 = (const float4*)&plds[w][0];
#pragma unroll 1
  for (int c2 = 0; c2 < 17; ++c2) {
    float4 pc = p4[c2];
    int l0 = c2 * 4;
#pragma unroll
    for (int t = 0; t < 4; ++t) {
      int j = i - 64 + l0 + t;
      j = j < 0 ? 0 : (j > S - 1 ? S - 1 : j);
      float pv = ((const float*)&pc)[t];
      o += pv * vcol[(size_t)j * QS];
    }
  }
  ao[(size_t)bs * (H * HD) + h * HD + lane] = f2bf(o);
}

// ---------------------------------------------------------------------------
extern "C" void kernel_launch(void* const* d_in, const int* in_sizes, int n_in,
                              void* d_out, int out_size, void* d_ws, size_t ws_size,
                              hipStream_t stream) {
  const float* x  = (const float*)d_in[0];
  const float* fc = (const float*)d_in[1];
  const float* fs = (const float*)d_in[2];
  const float* wq = (const float*)d_in[3];
  const float* wk = (const float*)d_in[4];
  const float* wv = (const float*)d_in[5];
  const float* wo = (const float*)d_in[6];
  float* out = (float*)d_out;

  // workspace: [xb 8MiB][wqkvT 3MiB][woT 2MiB][qkv 24MiB]; ao aliases xb
  char* base = (char*)d_ws;
  unsigned short* xb    = (unsigned short*)base;                         // 4096x1024 bf16
  unsigned short* wqkvT = (unsigned short*)(base + (8u << 20));          // 1536x1024 bf16
  unsigned short* woT   = (unsigned short*)(base + (11u << 20));         // 1024x1024 bf16
  float*          qkv   = (float*)(base + (13u << 20));                  // 4096x1536 fp32
  unsigned short* ao    = (unsigned short*)base;                         // 4096x1024 bf16 (aliases xb)

  // casts / transposes
  cast_x_kernel<<<(BS * D / 4) / 256, 256, 0, stream>>>(x, xb);
  transpose_cast_kernel<<<dim3(32, 32), dim3(32, 8), 0, stream>>>(wq, wqkvT, 1024, 0);
  transpose_cast_kernel<<<dim3(8, 32),  dim3(32, 8), 0, stream>>>(wk, wqkvT, 256, 1024);
  transpose_cast_kernel<<<dim3(8, 32),  dim3(32, 8), 0, stream>>>(wv, wqkvT, 256, 1280);
  transpose_cast_kernel<<<dim3(32, 32), dim3(32, 8), 0, stream>>>(wo, woT, 1024, 0);

  // fused QKV projection: [4096,1024] x [1536,1024]^T -> qkv fp32 [4096,1536]
  gemm_bt_kernel<<<dim3(QS / 128, BS / 128), 256, 0, stream>>>(xb, wqkvT, qkv, QS, D);

  // RoPE on q (16 heads) and k (4 heads)
  rope_kernel<<<(BS * H * 32) / 256, 256, 0, stream>>>(qkv, fc, fs, H, 0, BS * H * 32);
  rope_kernel<<<(BS * KVH * 32) / 256, 256, 0, stream>>>(qkv, fc, fs, KVH, KOFF, BS * KVH * 32);

  // fused attention -> ao bf16 [4096, 1024]
  attn_kernel<<<(BS * H) / 4, 256, 0, stream>>>(qkv, ao);

  // output projection: [4096,1024] x [1024,1024]^T -> out fp32
  gemm_bt_kernel<<<dim3(D / 128, BS / 128), 256, 0, stream>>>(ao, woT, out, D, D);
}

// Round 3
// 177.098 us; speedup vs baseline: 4.2412x; 1.9639x over previous
//
#include <hip/hip_runtime.h>
#include <hip/hip_bf16.h>

constexpr int B = 2, S = 2048, D = 1024;
constexpr int H = 16, KVH = 4, HD = 64;
constexpr int BS = B * S;                 // 4096
constexpr int QS = 1536;                  // qkv row stride
constexpr int VOFF = 1280;

typedef __attribute__((ext_vector_type(8))) short short8;
typedef __attribute__((ext_vector_type(4))) float floatx4;

static __device__ __forceinline__ unsigned short f2bf(float f) {
  union { float f; unsigned u; } c{f};
  unsigned r = (c.u + 0x7FFFu + ((c.u >> 16) & 1u)) >> 16;
  return (unsigned short)r;
}
static __device__ __forceinline__ float bf2f(unsigned short u) {
  union { unsigned u; float f; } c{(unsigned)u << 16};
  return c.f;
}

// ---------------------------------------------------------------------------
// x fp32 -> bf16
// ---------------------------------------------------------------------------
__global__ void cast_x_kernel(const float* __restrict__ x, unsigned short* __restrict__ xb) {
  int t = blockIdx.x * blockDim.x + threadIdx.x;
  float4 v = ((const float4*)x)[t];
  ushort4 o;
  o.x = f2bf(v.x); o.y = f2bf(v.y); o.z = f2bf(v.z); o.w = f2bf(v.w);
  ((ushort4*)xb)[t] = o;
}

// ---------------------------------------------------------------------------
// w fp32 [K=1024, N] row-major -> wT bf16 [N, 1024] at row offset dstOff
// ---------------------------------------------------------------------------
__global__ void transpose_cast_kernel(const float* __restrict__ src,
                                      unsigned short* __restrict__ dst,
                                      int N, int dstOff) {
  __shared__ float t[32][33];
  int n0 = blockIdx.x * 32, k0 = blockIdx.y * 32;
  int tx = threadIdx.x, ty = threadIdx.y;
#pragma unroll
  for (int r = 0; r < 4; ++r)
    t[ty + r * 8][tx] = src[(size_t)(k0 + ty + r * 8) * N + n0 + tx];
  __syncthreads();
#pragma unroll
  for (int r = 0; r < 4; ++r)
    dst[(size_t)(dstOff + n0 + ty + r * 8) * D + k0 + tx] = f2bf(t[tx][ty + r * 8]);
}

// ---------------------------------------------------------------------------
// bf16 MFMA GEMM: C[M,N] = A[M,K] * Bt[N,K]^T. 128x128 tile, BK=32.
// Output fp32 or bf16 per flag.
// ---------------------------------------------------------------------------
__global__ __launch_bounds__(256) void gemm_bt_kernel(
    const unsigned short* __restrict__ A, const unsigned short* __restrict__ Bt,
    void* __restrict__ Cv, int N, int K, int bf16out) {
  __shared__ unsigned short As[128 * 32];
  __shared__ unsigned short Bs[128 * 32];
  const int tid = threadIdx.x;
  const int lane = tid & 63, wvid = tid >> 6;
  const int wy = wvid >> 1, wx = wvid & 1;
  const int quad = lane >> 4, lrow = lane & 15;
  const size_t row0 = (size_t)blockIdx.y * 128;
  const size_t col0 = (size_t)blockIdx.x * 128;

  floatx4 zero4 = {0.f, 0.f, 0.f, 0.f};
  floatx4 acc[4][4];
#pragma unroll
  for (int i = 0; i < 4; ++i)
#pragma unroll
    for (int j = 0; j < 4; ++j) acc[i][j] = zero4;

  const int r1 = tid >> 2, cc1 = tid & 3;
  const int r2 = r1 + 64;

  for (int k0 = 0; k0 < K; k0 += 32) {
    uint4 a1 = *(const uint4*)&A[(row0 + r1) * K + k0 + cc1 * 8];
    uint4 a2 = *(const uint4*)&A[(row0 + r2) * K + k0 + cc1 * 8];
    uint4 b1 = *(const uint4*)&Bt[(col0 + r1) * K + k0 + cc1 * 8];
    uint4 b2 = *(const uint4*)&Bt[(col0 + r2) * K + k0 + cc1 * 8];
    __syncthreads();
    *(uint4*)&As[r1 * 32 + ((cc1 ^ (r1 & 3)) * 8)] = a1;
    *(uint4*)&As[r2 * 32 + ((cc1 ^ (r2 & 3)) * 8)] = a2;
    *(uint4*)&Bs[r1 * 32 + ((cc1 ^ (r1 & 3)) * 8)] = b1;
    *(uint4*)&Bs[r2 * 32 + ((cc1 ^ (r2 & 3)) * 8)] = b2;
    __syncthreads();

    short8 af[4], bg[4];
#pragma unroll
    for (int mi = 0; mi < 4; ++mi) {
      int m = wy * 64 + mi * 16 + lrow;
      af[mi] = *(const short8*)&As[m * 32 + ((quad ^ (m & 3)) * 8)];
    }
#pragma unroll
    for (int ni = 0; ni < 4; ++ni) {
      int n = wx * 64 + ni * 16 + lrow;
      bg[ni] = *(const short8*)&Bs[n * 32 + ((quad ^ (n & 3)) * 8)];
    }
#pragma unroll
    for (int mi = 0; mi < 4; ++mi)
#pragma unroll
      for (int ni = 0; ni < 4; ++ni)
        acc[mi][ni] = __builtin_amdgcn_mfma_f32_16x16x32_bf16(af[mi], bg[ni], acc[mi][ni], 0, 0, 0);
  }

  if (bf16out) {
    unsigned short* Cb = (unsigned short*)Cv;
#pragma unroll
    for (int mi = 0; mi < 4; ++mi)
#pragma unroll
      for (int ni = 0; ni < 4; ++ni) {
        size_t col = col0 + wx * 64 + ni * 16 + lrow;
        size_t rowb = row0 + wy * 64 + mi * 16 + quad * 4;
#pragma unroll
        for (int r = 0; r < 4; ++r)
          Cb[(rowb + r) * N + col] = f2bf(acc[mi][ni][r]);
      }
  } else {
    float* C = (float*)Cv;
#pragma unroll
    for (int mi = 0; mi < 4; ++mi)
#pragma unroll
      for (int ni = 0; ni < 4; ++ni) {
        size_t col = col0 + wx * 64 + ni * 16 + lrow;
        size_t rowb = row0 + wy * 64 + mi * 16 + quad * 4;
#pragma unroll
        for (int r = 0; r < 4; ++r)
          C[(rowb + r) * N + col] = acc[mi][ni][r];
      }
  }
}

// ---------------------------------------------------------------------------
// RoPE + repack: qkvb bf16 [BS,1536] -> dst bf16 [BS, nheads*64]
// ---------------------------------------------------------------------------
__global__ void rope_pack_kernel(const unsigned short* __restrict__ qkvb,
                                 const float* __restrict__ cs, const float* __restrict__ sn,
                                 unsigned short* __restrict__ dst,
                                 int nheads, int srcOff, int npairs) {
  int idx = blockIdx.x * blockDim.x + threadIdx.x;
  if (idx >= npairs) return;
  int f = idx & 31;
  int rest = idx >> 5;
  int nh = rest % nheads;
  int bs = rest / nheads;
  int s = bs & (S - 1);
  float c = cs[s * 32 + f], si = sn[s * 32 + f];
  const unsigned short* p = qkvb + (size_t)bs * QS + srcOff + nh * HD + 2 * f;
  float a = bf2f(p[0]), b = bf2f(p[1]);
  unsigned short o0 = f2bf(a * c - b * si);
  unsigned short o1 = f2bf(a * si + b * c);
  *(unsigned*)(dst + (size_t)bs * (nheads * HD) + nh * HD + 2 * f) =
      (unsigned)o0 | ((unsigned)o1 << 16);
}

// ---------------------------------------------------------------------------
// V transpose: qkvb v-part [bs][kvh*64] -> vT [b*KVH+kvh][64 d][S]
// ---------------------------------------------------------------------------
__global__ void vtrans_kernel(const unsigned short* __restrict__ qkvb,
                              unsigned short* __restrict__ vt) {
  __shared__ unsigned short t[32][34];
  int d0 = blockIdx.x * 32;
  int s0 = blockIdx.y * 32;
  int g = blockIdx.z;                  // b*KVH + kvh
  int b = g >> 2, kvh = g & 3;
  int tx = threadIdx.x, ty = threadIdx.y;
#pragma unroll
  for (int r = 0; r < 4; ++r)
    t[ty + r * 8][tx] = qkvb[(size_t)(b * S + s0 + ty + r * 8) * QS + VOFF + kvh * 64 + d0 + tx];
  __syncthreads();
#pragma unroll
  for (int r = 0; r < 4; ++r)
    vt[((size_t)g * 64 + d0 + ty + r * 8) * S + s0 + tx] = t[tx][ty + r * 8];
}

// ---------------------------------------------------------------------------
// MFMA flash attention. One wave per (b, h, 16-query block).
// Keys padded to 96 = 6 tiles of 16; jbase = i0-80 (front tile fully masked).
// QK^T: A=Q rows, B=K rows. PV computed as V^T x P^T so output is query-major.
// ---------------------------------------------------------------------------
__global__ __launch_bounds__(256) void attn_kernel(
    const unsigned short* __restrict__ qb,   // [BS][1024]
    const unsigned short* __restrict__ kb,   // [BS][256]
    const unsigned short* __restrict__ vt,   // [B*KVH][64][S]
    unsigned short* __restrict__ ao) {       // [BS][1024]
  __shared__ __align__(16) unsigned short plds[4][16][104];
  const int w = threadIdx.x >> 6, lane = threadIdx.x & 63;
  const int lrow = lane & 15, quad = lane >> 4;
  const int wg = blockIdx.x * 4 + w;
  const int h = wg & (H - 1);
  const int qblk = wg >> 4;
  const int i0 = (qblk & (S / 16 - 1)) * 16;
  const int b = qblk >> 7;                  // qblk / (S/16)
  const int kvh = h >> 2;
  const int jbase = i0 - 80;

  // Q A-frags (2 K-chunks over HD=64)
  const unsigned short* qrow = qb + (size_t)(b * S + i0 + lrow) * 1024 + h * 64 + quad * 8;
  short8 qf0 = *(const short8*)qrow;
  short8 qf1 = *(const short8*)(qrow + 32);

  // scores: 6 key tiles
  floatx4 sc[6];
#pragma unroll
  for (int t = 0; t < 6; ++t) {
    int j = jbase + t * 16 + lrow;
    int jc = j < 0 ? 0 : j;
    const unsigned short* krow = kb + (size_t)(b * S + jc) * 256 + kvh * 64 + quad * 8;
    short8 kf0 = *(const short8*)krow;
    short8 kf1 = *(const short8*)(krow + 32);
    floatx4 a = {0.f, 0.f, 0.f, 0.f};
    a = __builtin_amdgcn_mfma_f32_16x16x32_bf16(qf0, kf0, a, 0, 0, 0);
    a = __builtin_amdgcn_mfma_f32_16x16x32_bf16(qf1, kf1, a, 0, 0, 0);
    sc[t] = a;
  }

  // mask + scale; rows i = i0 + quad*4 + r, cols j = jbase + t*16 + lrow
  float sv[6][4];
  float mx[4] = {-1e30f, -1e30f, -1e30f, -1e30f};
#pragma unroll
  for (int t = 0; t < 6; ++t) {
    int j = jbase + t * 16 + lrow;
#pragma unroll
    for (int r = 0; r < 4; ++r) {
      int dji = (i0 + quad * 4 + r) - j;
      bool valid = (j >= 0) && (dji >= 0) && (dji <= 64);
      float s = valid ? sc[t][r] * 0.125f : -1e30f;
      sv[t][r] = s;
      mx[r] = fmaxf(mx[r], s);
    }
  }
#pragma unroll
  for (int r = 0; r < 4; ++r)
#pragma unroll
    for (int off = 8; off > 0; off >>= 1)
      mx[r] = fmaxf(mx[r], __shfl_xor(mx[r], off));

  float ls[4] = {0.f, 0.f, 0.f, 0.f};
#pragma unroll
  for (int t = 0; t < 6; ++t)
#pragma unroll
    for (int r = 0; r < 4; ++r) {
      float e = __expf(sv[t][r] - mx[r]);
      sv[t][r] = e;
      ls[r] += e;
    }
#pragma unroll
  for (int r = 0; r < 4; ++r) {
#pragma unroll
    for (int off = 8; off > 0; off >>= 1)
      ls[r] += __shfl_xor(ls[r], off);
    ls[r] = 1.f / ls[r];
  }
#pragma unroll
  for (int t = 0; t < 6; ++t)
#pragma unroll
    for (int r = 0; r < 4; ++r)
      plds[w][quad * 4 + r][t * 16 + lrow] = f2bf(sv[t][r] * ls[r]);
  __syncthreads();

  // PV: D[m=d][n=q] = sum_j vT[d,j] * P[q,j]
  floatx4 oc[4];
#pragma unroll
  for (int mt = 0; mt < 4; ++mt) oc[mt] = floatx4{0.f, 0.f, 0.f, 0.f};
  const unsigned short* vbase = vt + (size_t)(b * KVH + kvh) * 64 * S;
#pragma unroll
  for (int c = 0; c < 3; ++c) {
    short8 pf = *(const short8*)&plds[w][lrow][c * 32 + quad * 8];
    int j = jbase + c * 32 + quad * 8;
    int jc = j < 0 ? 0 : j;               // j<0 chunks have P=0 (front pad)
#pragma unroll
    for (int mt = 0; mt < 4; ++mt) {
      short8 vf = *(const short8*)(vbase + (size_t)(mt * 16 + lrow) * S + jc);
      oc[mt] = __builtin_amdgcn_mfma_f32_16x16x32_bf16(vf, pf, oc[mt], 0, 0, 0);
    }
  }

  // epilogue: col = lane&15 = q, rows quad*4+r = d-in-tile -> 8B stores
#pragma unroll
  for (int mt = 0; mt < 4; ++mt) {
    ushort4 o;
    o.x = f2bf(oc[mt][0]); o.y = f2bf(oc[mt][1]);
    o.z = f2bf(oc[mt][2]); o.w = f2bf(oc[mt][3]);
    *(ushort4*)(ao + (size_t)(b * S + i0 + lrow) * 1024 + h * 64 + mt * 16 + quad * 4) = o;
  }
}

// ---------------------------------------------------------------------------
extern "C" void kernel_launch(void* const* d_in, const int* in_sizes, int n_in,
                              void* d_out, int out_size, void* d_ws, size_t ws_size,
                              hipStream_t stream) {
  const float* x  = (const float*)d_in[0];
  const float* fc = (const float*)d_in[1];
  const float* fs = (const float*)d_in[2];
  const float* wq = (const float*)d_in[3];
  const float* wk = (const float*)d_in[4];
  const float* wv = (const float*)d_in[5];
  const float* wo = (const float*)d_in[6];
  float* out = (float*)d_out;

  // ws: [xb/qb 8M][wqkvT 3M][woT 2M][qkvb 12M][kb 2M][vT 2M][ao 8M] = 37 MiB
  char* base = (char*)d_ws;
  unsigned short* xb    = (unsigned short*)base;                    // aliased by qb
  unsigned short* qb    = (unsigned short*)base;
  unsigned short* wqkvT = (unsigned short*)(base + (8u << 20));
  unsigned short* woT   = (unsigned short*)(base + (11u << 20));
  unsigned short* qkvb  = (unsigned short*)(base + (13u << 20));
  unsigned short* kb    = (unsigned short*)(base + (25u << 20));
  unsigned short* vT    = (unsigned short*)(base + (27u << 20));
  unsigned short* ao    = (unsigned short*)(base + (29u << 20));

  cast_x_kernel<<<(BS * D / 4) / 256, 256, 0, stream>>>(x, xb);
  transpose_cast_kernel<<<dim3(32, 32), dim3(32, 8), 0, stream>>>(wq, wqkvT, 1024, 0);
  transpose_cast_kernel<<<dim3(8, 32),  dim3(32, 8), 0, stream>>>(wk, wqkvT, 256, 1024);
  transpose_cast_kernel<<<dim3(8, 32),  dim3(32, 8), 0, stream>>>(wv, wqkvT, 256, 1280);
  transpose_cast_kernel<<<dim3(32, 32), dim3(32, 8), 0, stream>>>(wo, woT, 1024, 0);

  // fused QKV projection -> bf16 [4096,1536]
  gemm_bt_kernel<<<dim3(QS / 128, BS / 128), 256, 0, stream>>>(xb, wqkvT, qkvb, QS, D, 1);

  // RoPE + pack q [BS,1024], k [BS,256]; V transpose -> [8][64][2048]
  rope_pack_kernel<<<(BS * H * 32) / 256, 256, 0, stream>>>(qkvb, fc, fs, qb, H, 0, BS * H * 32);
  rope_pack_kernel<<<(BS * KVH * 32) / 256, 256, 0, stream>>>(qkvb, fc, fs, kb, KVH, 1024, BS * KVH * 32);
  vtrans_kernel<<<dim3(2, S / 32, B * KVH), dim3(32, 8), 0, stream>>>(qkvb, vT);

  // MFMA attention -> ao bf16 [4096,1024]
  attn_kernel<<<(BS / 16) * H / 4, 256, 0, stream>>>(qb, kb, vT, ao);

  // output projection -> fp32
  gemm_bt_kernel<<<dim3(D / 128, BS / 128), 256, 0, stream>>>(ao, woT, out, D, D, 0);
}

// Round 4
// 170.332 us; speedup vs baseline: 4.4097x; 1.0397x over previous
//
#include <hip/hip_runtime.h>
#include <hip/hip_bf16.h>

constexpr int B = 2, S = 2048, D = 1024;
constexpr int H = 16, KVH = 4, HD = 64;
constexpr int BS = B * S;                 // 4096
constexpr int QS = 1536;                  // qkv row stride
constexpr int VOFF = 1280;

typedef __attribute__((ext_vector_type(8))) short short8;
typedef __attribute__((ext_vector_type(4))) float floatx4;

#define GPTR(p) ((__attribute__((address_space(1))) void*)(p))
#define LPTR(p) ((__attribute__((address_space(3))) void*)(p))

static __device__ __forceinline__ unsigned short f2bf(float f) {
  union { float f; unsigned u; } c{f};
  unsigned r = (c.u + 0x7FFFu + ((c.u >> 16) & 1u)) >> 16;
  return (unsigned short)r;
}
static __device__ __forceinline__ float bf2f(unsigned short u) {
  union { unsigned u; float f; } c{(unsigned)u << 16};
  return c.f;
}

// ---------------------------------------------------------------------------
// x fp32 -> bf16
// ---------------------------------------------------------------------------
__global__ void cast_x_kernel(const float* __restrict__ x, unsigned short* __restrict__ xb) {
  int t = blockIdx.x * blockDim.x + threadIdx.x;
  float4 v = ((const float4*)x)[t];
  ushort4 o;
  o.x = f2bf(v.x); o.y = f2bf(v.y); o.z = f2bf(v.z); o.w = f2bf(v.w);
  ((ushort4*)xb)[t] = o;
}

// ---------------------------------------------------------------------------
// All 4 weight transposes in one launch. fp32 [K=1024, N] -> bf16 [N,1024].
// blockIdx.x regions: [0,32) wq | [32,40) wk | [40,48) wv | [48,80) wo
// ---------------------------------------------------------------------------
__global__ void wtrans_kernel(const float* __restrict__ wq, const float* __restrict__ wk,
                              const float* __restrict__ wv, const float* __restrict__ wo,
                              unsigned short* __restrict__ wqkvT, unsigned short* __restrict__ woT) {
  __shared__ float t[32][33];
  int z = blockIdx.x;
  const float* src; unsigned short* dst; int N, dstOff, nb;
  if (z < 32)      { src = wq; dst = wqkvT; N = 1024; dstOff = 0;    nb = z; }
  else if (z < 40) { src = wk; dst = wqkvT; N = 256;  dstOff = 1024; nb = z - 32; }
  else if (z < 48) { src = wv; dst = wqkvT; N = 256;  dstOff = 1280; nb = z - 40; }
  else             { src = wo; dst = woT;   N = 1024; dstOff = 0;    nb = z - 48; }
  int n0 = nb * 32, k0 = blockIdx.y * 32;
  int tx = threadIdx.x, ty = threadIdx.y;
#pragma unroll
  for (int r = 0; r < 4; ++r)
    t[ty + r * 8][tx] = src[(size_t)(k0 + ty + r * 8) * N + n0 + tx];
  __syncthreads();
#pragma unroll
  for (int r = 0; r < 4; ++r)
    dst[(size_t)(dstOff + n0 + ty + r * 8) * D + k0 + tx] = f2bf(t[tx][ty + r * 8]);
}

// ---------------------------------------------------------------------------
// bf16 MFMA GEMM (m97 structure): C[M,N] = A[M,K] * Bt[N,K]^T.
// 128x128 tile, BK=32, 4 waves. global_load_lds width=16 staging into linear
// LDS [row][32]; lane l of wave w lands at byte w*2048 + l*16 (= row-major).
// ---------------------------------------------------------------------------
__global__ __launch_bounds__(256) void gemm_bt_kernel(
    const unsigned short* __restrict__ A, const unsigned short* __restrict__ Bt,
    void* __restrict__ Cv, int N, int K, int bf16out) {
  __shared__ unsigned short As[128 * 32];
  __shared__ unsigned short Bs[128 * 32];
  const int tid = threadIdx.x;
  const int lane = tid & 63, wvid = tid >> 6;
  const int wy = wvid >> 1, wx = wvid & 1;
  const int quad = lane >> 4, lrow = lane & 15;
  const size_t row0 = (size_t)blockIdx.y * 128;
  const size_t col0 = (size_t)blockIdx.x * 128;

  floatx4 zero4 = {0.f, 0.f, 0.f, 0.f};
  floatx4 acc[4][4];
#pragma unroll
  for (int i = 0; i < 4; ++i)
#pragma unroll
    for (int j = 0; j < 4; ++j) acc[i][j] = zero4;

  // staging: wave w covers rows [w*32, w*32+32) in two 16-row calls
  const int srow = wvid * 32 + (lane >> 2);
  const int schk = (lane & 3) * 8;
  const unsigned short* ga0 = A  + (row0 + srow) * K + schk;
  const unsigned short* ga1 = ga0 + 16 * K;
  const unsigned short* gb0 = Bt + (col0 + srow) * K + schk;
  const unsigned short* gb1 = gb0 + 16 * K;
  char* ldsA = (char*)As + wvid * 2048;
  char* ldsB = (char*)Bs + wvid * 2048;

  for (int k0 = 0; k0 < K; k0 += 32) {
    __syncthreads();
    __builtin_amdgcn_global_load_lds(GPTR(ga0 + k0), LPTR(ldsA), 16, 0, 0);
    __builtin_amdgcn_global_load_lds(GPTR(ga1 + k0), LPTR(ldsA + 1024), 16, 0, 0);
    __builtin_amdgcn_global_load_lds(GPTR(gb0 + k0), LPTR(ldsB), 16, 0, 0);
    __builtin_amdgcn_global_load_lds(GPTR(gb1 + k0), LPTR(ldsB + 1024), 16, 0, 0);
    __syncthreads();

    short8 af[4], bg[4];
#pragma unroll
    for (int mi = 0; mi < 4; ++mi)
      af[mi] = *(const short8*)&As[(wy * 64 + mi * 16 + lrow) * 32 + quad * 8];
#pragma unroll
    for (int ni = 0; ni < 4; ++ni)
      bg[ni] = *(const short8*)&Bs[(wx * 64 + ni * 16 + lrow) * 32 + quad * 8];
#pragma unroll
    for (int mi = 0; mi < 4; ++mi)
#pragma unroll
      for (int ni = 0; ni < 4; ++ni)
        acc[mi][ni] = __builtin_amdgcn_mfma_f32_16x16x32_bf16(af[mi], bg[ni], acc[mi][ni], 0, 0, 0);
  }

  if (bf16out) {
    unsigned short* Cb = (unsigned short*)Cv;
#pragma unroll
    for (int mi = 0; mi < 4; ++mi)
#pragma unroll
      for (int ni = 0; ni < 4; ++ni) {
        size_t col = col0 + wx * 64 + ni * 16 + lrow;
        size_t rowb = row0 + wy * 64 + mi * 16 + quad * 4;
#pragma unroll
        for (int r = 0; r < 4; ++r)
          Cb[(rowb + r) * N + col] = f2bf(acc[mi][ni][r]);
      }
  } else {
    float* C = (float*)Cv;
#pragma unroll
    for (int mi = 0; mi < 4; ++mi)
#pragma unroll
      for (int ni = 0; ni < 4; ++ni) {
        size_t col = col0 + wx * 64 + ni * 16 + lrow;
        size_t rowb = row0 + wy * 64 + mi * 16 + quad * 4;
#pragma unroll
        for (int r = 0; r < 4; ++r)
          C[(rowb + r) * N + col] = acc[mi][ni][r];
      }
  }
}

// ---------------------------------------------------------------------------
// RoPE + repack for q AND k in one launch: qkvb [BS,1536] -> qb [BS,1024],
// kb [BS,256]. Virtual head index nh in [0,20): <16 = q head, else k head.
// ---------------------------------------------------------------------------
__global__ void rope_kernel(const unsigned short* __restrict__ qkvb,
                            const float* __restrict__ cs, const float* __restrict__ sn,
                            unsigned short* __restrict__ qb, unsigned short* __restrict__ kb) {
  int idx = blockIdx.x * blockDim.x + threadIdx.x;   // BS*20*32 total
  int f = idx & 31;
  int rest = idx >> 5;
  int nh = rest % 20;
  int bs = rest / 20;
  int s = bs & (S - 1);
  float c = cs[s * 32 + f], si = sn[s * 32 + f];
  const unsigned short* p;
  unsigned short* d;
  if (nh < 16) {
    p = qkvb + (size_t)bs * QS + nh * HD + 2 * f;
    d = qb + (size_t)bs * 1024 + nh * HD + 2 * f;
  } else {
    p = qkvb + (size_t)bs * QS + 1024 + (nh - 16) * HD + 2 * f;
    d = kb + (size_t)bs * 256 + (nh - 16) * HD + 2 * f;
  }
  float a = bf2f(p[0]), b = bf2f(p[1]);
  unsigned short o0 = f2bf(a * c - b * si);
  unsigned short o1 = f2bf(a * si + b * c);
  *(unsigned*)d = (unsigned)o0 | ((unsigned)o1 << 16);
}

// ---------------------------------------------------------------------------
// V transpose: qkvb v-part [bs][kvh*64] -> vT [b*KVH+kvh][64 d][S]
// ---------------------------------------------------------------------------
__global__ void vtrans_kernel(const unsigned short* __restrict__ qkvb,
                              unsigned short* __restrict__ vt) {
  __shared__ unsigned short t[32][34];
  int d0 = blockIdx.x * 32;
  int s0 = blockIdx.y * 32;
  int g = blockIdx.z;                  // b*KVH + kvh
  int b = g >> 2, kvh = g & 3;
  int tx = threadIdx.x, ty = threadIdx.y;
#pragma unroll
  for (int r = 0; r < 4; ++r)
    t[ty + r * 8][tx] = qkvb[(size_t)(b * S + s0 + ty + r * 8) * QS + VOFF + kvh * 64 + d0 + tx];
  __syncthreads();
#pragma unroll
  for (int r = 0; r < 4; ++r)
    vt[((size_t)g * 64 + d0 + ty + r * 8) * S + s0 + tx] = t[tx][ty + r * 8];
}

// ---------------------------------------------------------------------------
// MFMA flash attention. One wave per (b, h, 16-query block).
// ---------------------------------------------------------------------------
__global__ __launch_bounds__(256) void attn_kernel(
    const unsigned short* __restrict__ qb,   // [BS][1024]
    const unsigned short* __restrict__ kb,   // [BS][256]
    const unsigned short* __restrict__ vt,   // [B*KVH][64][S]
    unsigned short* __restrict__ ao) {       // [BS][1024]
  __shared__ __align__(16) unsigned short plds[4][16][104];
  const int w = threadIdx.x >> 6, lane = threadIdx.x & 63;
  const int lrow = lane & 15, quad = lane >> 4;
  const int wg = blockIdx.x * 4 + w;
  const int h = wg & (H - 1);
  const int qblk = wg >> 4;
  const int i0 = (qblk & (S / 16 - 1)) * 16;
  const int b = qblk >> 7;
  const int kvh = h >> 2;
  const int jbase = i0 - 80;

  const unsigned short* qrow = qb + (size_t)(b * S + i0 + lrow) * 1024 + h * 64 + quad * 8;
  short8 qf0 = *(const short8*)qrow;
  short8 qf1 = *(const short8*)(qrow + 32);

  floatx4 sc[6];
#pragma unroll
  for (int t = 0; t < 6; ++t) {
    int j = jbase + t * 16 + lrow;
    int jc = j < 0 ? 0 : j;
    const unsigned short* krow = kb + (size_t)(b * S + jc) * 256 + kvh * 64 + quad * 8;
    short8 kf0 = *(const short8*)krow;
    short8 kf1 = *(const short8*)(krow + 32);
    floatx4 a = {0.f, 0.f, 0.f, 0.f};
    a = __builtin_amdgcn_mfma_f32_16x16x32_bf16(qf0, kf0, a, 0, 0, 0);
    a = __builtin_amdgcn_mfma_f32_16x16x32_bf16(qf1, kf1, a, 0, 0, 0);
    sc[t] = a;
  }

  float sv[6][4];
  float mx[4] = {-1e30f, -1e30f, -1e30f, -1e30f};
#pragma unroll
  for (int t = 0; t < 6; ++t) {
    int j = jbase + t * 16 + lrow;
#pragma unroll
    for (int r = 0; r < 4; ++r) {
      int dji = (i0 + quad * 4 + r) - j;
      bool valid = (j >= 0) && (dji >= 0) && (dji <= 64);
      float s = valid ? sc[t][r] * 0.125f : -1e30f;
      sv[t][r] = s;
      mx[r] = fmaxf(mx[r], s);
    }
  }
#pragma unroll
  for (int r = 0; r < 4; ++r)
#pragma unroll
    for (int off = 8; off > 0; off >>= 1)
      mx[r] = fmaxf(mx[r], __shfl_xor(mx[r], off));

  float ls[4] = {0.f, 0.f, 0.f, 0.f};
#pragma unroll
  for (int t = 0; t < 6; ++t)
#pragma unroll
    for (int r = 0; r < 4; ++r) {
      float e = __expf(sv[t][r] - mx[r]);
      sv[t][r] = e;
      ls[r] += e;
    }
#pragma unroll
  for (int r = 0; r < 4; ++r) {
#pragma unroll
    for (int off = 8; off > 0; off >>= 1)
      ls[r] += __shfl_xor(ls[r], off);
    ls[r] = 1.f / ls[r];
  }
#pragma unroll
  for (int t = 0; t < 6; ++t)
#pragma unroll
    for (int r = 0; r < 4; ++r)
      plds[w][quad * 4 + r][t * 16 + lrow] = f2bf(sv[t][r] * ls[r]);
  __syncthreads();

  floatx4 oc[4];
#pragma unroll
  for (int mt = 0; mt < 4; ++mt) oc[mt] = floatx4{0.f, 0.f, 0.f, 0.f};
  const unsigned short* vbase = vt + (size_t)(b * KVH + kvh) * 64 * S;
#pragma unroll
  for (int c = 0; c < 3; ++c) {
    short8 pf = *(const short8*)&plds[w][lrow][c * 32 + quad * 8];
    int j = jbase + c * 32 + quad * 8;
    int jc = j < 0 ? 0 : j;
#pragma unroll
    for (int mt = 0; mt < 4; ++mt) {
      short8 vf = *(const short8*)(vbase + (size_t)(mt * 16 + lrow) * S + jc);
      oc[mt] = __builtin_amdgcn_mfma_f32_16x16x32_bf16(vf, pf, oc[mt], 0, 0, 0);
    }
  }

#pragma unroll
  for (int mt = 0; mt < 4; ++mt) {
    ushort4 o;
    o.x = f2bf(oc[mt][0]); o.y = f2bf(oc[mt][1]);
    o.z = f2bf(oc[mt][2]); o.w = f2bf(oc[mt][3]);
    *(ushort4*)(ao + (size_t)(b * S + i0 + lrow) * 1024 + h * 64 + mt * 16 + quad * 4) = o;
  }
}

// ---------------------------------------------------------------------------
extern "C" void kernel_launch(void* const* d_in, const int* in_sizes, int n_in,
                              void* d_out, int out_size, void* d_ws, size_t ws_size,
                              hipStream_t stream) {
  const float* x  = (const float*)d_in[0];
  const float* fc = (const float*)d_in[1];
  const float* fs = (const float*)d_in[2];
  const float* wq = (const float*)d_in[3];
  const float* wk = (const float*)d_in[4];
  const float* wv = (const float*)d_in[5];
  const float* wo = (const float*)d_in[6];
  float* out = (float*)d_out;

  // ws: [xb/qb 8M][wqkvT 3M][woT 2M][qkvb 12M][kb 2M][vT 2M][ao 8M] = 37 MiB
  char* base = (char*)d_ws;
  unsigned short* xb    = (unsigned short*)base;                    // aliased by qb
  unsigned short* qb    = (unsigned short*)base;
  unsigned short* wqkvT = (unsigned short*)(base + (8u << 20));
  unsigned short* woT   = (unsigned short*)(base + (11u << 20));
  unsigned short* qkvb  = (unsigned short*)(base + (13u << 20));
  unsigned short* kb    = (unsigned short*)(base + (25u << 20));
  unsigned short* vT    = (unsigned short*)(base + (27u << 20));
  unsigned short* ao    = (unsigned short*)(base + (29u << 20));

  cast_x_kernel<<<(BS * D / 4) / 256, 256, 0, stream>>>(x, xb);
  wtrans_kernel<<<dim3(80, 32), dim3(32, 8), 0, stream>>>(wq, wk, wv, wo, wqkvT, woT);

  // fused QKV projection -> bf16 [4096,1536]
  gemm_bt_kernel<<<dim3(QS / 128, BS / 128), 256, 0, stream>>>(xb, wqkvT, qkvb, QS, D, 1);

  // RoPE+pack (q and k) and V transpose
  rope_kernel<<<(BS * 20 * 32) / 256, 256, 0, stream>>>(qkvb, fc, fs, qb, kb);
  vtrans_kernel<<<dim3(2, S / 32, B * KVH), dim3(32, 8), 0, stream>>>(qkvb, vT);

  // MFMA attention -> ao bf16 [4096,1024]
  attn_kernel<<<(BS / 16) * H / 4, 256, 0, stream>>>(qb, kb, vT, ao);

  // output projection -> fp32
  gemm_bt_kernel<<<dim3(D / 128, BS / 128), 256, 0, stream>>>(ao, woT, out, D, D, 0);
}

// Round 5
// 154.720 us; speedup vs baseline: 4.8546x; 1.1009x over previous
//
#include <hip/hip_runtime.h>
#include <hip/hip_bf16.h>

constexpr int B = 2, S = 2048, D = 1024;
constexpr int H = 16, KVH = 4, HD = 64;
constexpr int BS = B * S;                 // 4096
constexpr int QS = 1536;                  // fused qkv width

typedef __attribute__((ext_vector_type(8))) short short8;
typedef __attribute__((ext_vector_type(4))) float floatx4;

#define GPTR(p) ((__attribute__((address_space(1))) void*)(p))
#define LPTR(p) ((__attribute__((address_space(3))) void*)(p))

static __device__ __forceinline__ unsigned short f2bf(float f) {
  union { float f; unsigned u; } c{f};
  unsigned r = (c.u + 0x7FFFu + ((c.u >> 16) & 1u)) >> 16;
  return (unsigned short)r;
}

// ---------------------------------------------------------------------------
// Prep: x fp32 -> bf16 (blocks [0,4096)) and all 4 weight transposes
// (blocks [4096, 4096+2560)). fp32 [K=1024,N] -> bf16 [N,1024].
// ---------------------------------------------------------------------------
__global__ __launch_bounds__(256) void prep_kernel(
    const float* __restrict__ x,
    const float* __restrict__ wq, const float* __restrict__ wk,
    const float* __restrict__ wv, const float* __restrict__ wo,
    unsigned short* __restrict__ xb,
    unsigned short* __restrict__ wqkvT, unsigned short* __restrict__ woT) {
  int bz = blockIdx.x;
  if (bz < 4096) {
    int t = bz * 256 + threadIdx.x;
    float4 v = ((const float4*)x)[t];
    ushort4 o;
    o.x = f2bf(v.x); o.y = f2bf(v.y); o.z = f2bf(v.z); o.w = f2bf(v.w);
    ((ushort4*)xb)[t] = o;
    return;
  }
  __shared__ float t[32][33];
  int z = bz - 4096;                 // 0..2559
  int zx = z % 80, zy = z / 80;      // region-select, k-block
  const float* src; unsigned short* dst; int N, dstOff, nb;
  if (zx < 32)      { src = wq; dst = wqkvT; N = 1024; dstOff = 0;    nb = zx; }
  else if (zx < 40) { src = wk; dst = wqkvT; N = 256;  dstOff = 1024; nb = zx - 32; }
  else if (zx < 48) { src = wv; dst = wqkvT; N = 256;  dstOff = 1280; nb = zx - 40; }
  else              { src = wo; dst = woT;   N = 1024; dstOff = 0;    nb = zx - 48; }
  int n0 = nb * 32, k0 = zy * 32;
  int tx = threadIdx.x & 31, ty = threadIdx.x >> 5;
#pragma unroll
  for (int r = 0; r < 4; ++r)
    t[ty + r * 8][tx] = src[(size_t)(k0 + ty + r * 8) * N + n0 + tx];
  __syncthreads();
#pragma unroll
  for (int r = 0; r < 4; ++r)
    dst[(size_t)(dstOff + n0 + ty + r * 8) * D + k0 + tx] = f2bf(t[tx][ty + r * 8]);
}

// ---------------------------------------------------------------------------
// Fused QKV GEMM + RoPE + V-transpose.
// C[4096,1536] = xb[4096,1024] * wqkvT[1536,1024]^T, never materialized:
// each wave's 64-col span is one head (wave-uniform q/k/v branch).
//  - q heads (col<1024):  RoPE on fp32 acc -> qb [BS,1024]
//  - k heads (1024..1280): RoPE -> kb [BS,256]
//  - v heads (1280..1536): transposed store -> vT [B*KVH][64][S]
// RoPE pair partner lives in lane^1 (col parity = lrow parity).
// ---------------------------------------------------------------------------
__global__ __launch_bounds__(256) void gemm_qkv_kernel(
    const unsigned short* __restrict__ A, const unsigned short* __restrict__ Bt,
    const float* __restrict__ cs, const float* __restrict__ sn,
    unsigned short* __restrict__ qb, unsigned short* __restrict__ kb,
    unsigned short* __restrict__ vt) {
  constexpr int K = 1024;
  __shared__ unsigned short As[128 * 32];
  __shared__ unsigned short Bs[128 * 32];
  const int tid = threadIdx.x;
  const int lane = tid & 63, wvid = tid >> 6;
  const int wy = wvid >> 1, wx = wvid & 1;
  const int quad = lane >> 4, lrow = lane & 15;
  const size_t row0 = (size_t)blockIdx.y * 128;
  const size_t col0 = (size_t)blockIdx.x * 128;

  floatx4 acc[4][4];
#pragma unroll
  for (int i = 0; i < 4; ++i)
#pragma unroll
    for (int j = 0; j < 4; ++j) acc[i][j] = floatx4{0.f, 0.f, 0.f, 0.f};

  const int srow = wvid * 32 + (lane >> 2);
  const int schk = (lane & 3) * 8;
  const unsigned short* ga0 = A  + (row0 + srow) * K + schk;
  const unsigned short* ga1 = ga0 + 16 * K;
  const unsigned short* gb0 = Bt + (col0 + srow) * K + schk;
  const unsigned short* gb1 = gb0 + 16 * K;
  char* ldsA = (char*)As + wvid * 2048;
  char* ldsB = (char*)Bs + wvid * 2048;

  for (int k0 = 0; k0 < K; k0 += 32) {
    __syncthreads();
    __builtin_amdgcn_global_load_lds(GPTR(ga0 + k0), LPTR(ldsA), 16, 0, 0);
    __builtin_amdgcn_global_load_lds(GPTR(ga1 + k0), LPTR(ldsA + 1024), 16, 0, 0);
    __builtin_amdgcn_global_load_lds(GPTR(gb0 + k0), LPTR(ldsB), 16, 0, 0);
    __builtin_amdgcn_global_load_lds(GPTR(gb1 + k0), LPTR(ldsB + 1024), 16, 0, 0);
    __syncthreads();

    short8 af[4], bg[4];
#pragma unroll
    for (int mi = 0; mi < 4; ++mi)
      af[mi] = *(const short8*)&As[(wy * 64 + mi * 16 + lrow) * 32 + quad * 8];
#pragma unroll
    for (int ni = 0; ni < 4; ++ni)
      bg[ni] = *(const short8*)&Bs[(wx * 64 + ni * 16 + lrow) * 32 + quad * 8];
#pragma unroll
    for (int mi = 0; mi < 4; ++mi)
#pragma unroll
      for (int ni = 0; ni < 4; ++ni)
        acc[mi][ni] = __builtin_amdgcn_mfma_f32_16x16x32_bf16(af[mi], bg[ni], acc[mi][ni], 0, 0, 0);
  }

  const int col_wave = (int)col0 + wx * 64;   // head-aligned, wave-uniform
  const int h = col_wave >> 6;
  const int sb = (int)(row0 & 2047) + wy * 64;  // seq base for this wave
  const int bidx = (int)(row0 >> 11);           // batch (tile never straddles)

  if (h < 20) {
    // q or k head: RoPE on fp32 acc, partner value in lane^1
    unsigned short* dst = (h < 16) ? qb : kb;
    const int dstride = (h < 16) ? 1024 : 256;
    const int dcol = (h < 16) ? (col_wave + 0) : (col_wave - 1024);
    const int f = (lrow + 0) >> 1;              // pair index base (per ni: +8*ni)
    const bool ev = (lrow & 1) == 0;
#pragma unroll
    for (int mi = 0; mi < 4; ++mi) {
#pragma unroll
      for (int ni = 0; ni < 4; ++ni) {
        int ff = (ni * 16 + lrow) >> 1;
#pragma unroll
        for (int r = 0; r < 4; ++r) {
          int s = sb + mi * 16 + quad * 4 + r;
          float v = acc[mi][ni][r];
          float p = __shfl_xor(v, 1);
          float c = cs[s * 32 + ff];
          float si = sn[s * 32 + ff];
          float o = ev ? (v * c - p * si) : (v * c + p * si);
          size_t row = row0 + wy * 64 + mi * 16 + quad * 4 + r;
          dst[row * dstride + dcol + ni * 16 + lrow] = f2bf(o);
        }
      }
    }
    (void)f;
  } else {
    // v head: transposed store vt[(g*64 + d)][s], 4 consecutive s per store
    const int kvh = h - 20;
    const int g = bidx * KVH + kvh;
#pragma unroll
    for (int mi = 0; mi < 4; ++mi) {
#pragma unroll
      for (int ni = 0; ni < 4; ++ni) {
        int d = ni * 16 + lrow;
        int s0 = sb + mi * 16 + quad * 4;
        ushort4 o;
        o.x = f2bf(acc[mi][ni][0]); o.y = f2bf(acc[mi][ni][1]);
        o.z = f2bf(acc[mi][ni][2]); o.w = f2bf(acc[mi][ni][3]);
        *(ushort4*)&vt[((size_t)(g * 64 + d)) * S + s0] = o;
      }
    }
  }
}

// ---------------------------------------------------------------------------
// bf16 MFMA GEMM (m97 structure) for the output projection -> fp32 C.
// ---------------------------------------------------------------------------
__global__ __launch_bounds__(256) void gemm_bt_kernel(
    const unsigned short* __restrict__ A, const unsigned short* __restrict__ Bt,
    float* __restrict__ C, int N, int K) {
  __shared__ unsigned short As[128 * 32];
  __shared__ unsigned short Bs[128 * 32];
  const int tid = threadIdx.x;
  const int lane = tid & 63, wvid = tid >> 6;
  const int wy = wvid >> 1, wx = wvid & 1;
  const int quad = lane >> 4, lrow = lane & 15;
  const size_t row0 = (size_t)blockIdx.y * 128;
  const size_t col0 = (size_t)blockIdx.x * 128;

  floatx4 acc[4][4];
#pragma unroll
  for (int i = 0; i < 4; ++i)
#pragma unroll
    for (int j = 0; j < 4; ++j) acc[i][j] = floatx4{0.f, 0.f, 0.f, 0.f};

  const int srow = wvid * 32 + (lane >> 2);
  const int schk = (lane & 3) * 8;
  const unsigned short* ga0 = A  + (row0 + srow) * K + schk;
  const unsigned short* ga1 = ga0 + 16 * K;
  const unsigned short* gb0 = Bt + (col0 + srow) * K + schk;
  const unsigned short* gb1 = gb0 + 16 * K;
  char* ldsA = (char*)As + wvid * 2048;
  char* ldsB = (char*)Bs + wvid * 2048;

  for (int k0 = 0; k0 < K; k0 += 32) {
    __syncthreads();
    __builtin_amdgcn_global_load_lds(GPTR(ga0 + k0), LPTR(ldsA), 16, 0, 0);
    __builtin_amdgcn_global_load_lds(GPTR(ga1 + k0), LPTR(ldsA + 1024), 16, 0, 0);
    __builtin_amdgcn_global_load_lds(GPTR(gb0 + k0), LPTR(ldsB), 16, 0, 0);
    __builtin_amdgcn_global_load_lds(GPTR(gb1 + k0), LPTR(ldsB + 1024), 16, 0, 0);
    __syncthreads();

    short8 af[4], bg[4];
#pragma unroll
    for (int mi = 0; mi < 4; ++mi)
      af[mi] = *(const short8*)&As[(wy * 64 + mi * 16 + lrow) * 32 + quad * 8];
#pragma unroll
    for (int ni = 0; ni < 4; ++ni)
      bg[ni] = *(const short8*)&Bs[(wx * 64 + ni * 16 + lrow) * 32 + quad * 8];
#pragma unroll
    for (int mi = 0; mi < 4; ++mi)
#pragma unroll
      for (int ni = 0; ni < 4; ++ni)
        acc[mi][ni] = __builtin_amdgcn_mfma_f32_16x16x32_bf16(af[mi], bg[ni], acc[mi][ni], 0, 0, 0);
  }

#pragma unroll
  for (int mi = 0; mi < 4; ++mi)
#pragma unroll
    for (int ni = 0; ni < 4; ++ni) {
      size_t col = col0 + wx * 64 + ni * 16 + lrow;
      size_t rowb = row0 + wy * 64 + mi * 16 + quad * 4;
#pragma unroll
      for (int r = 0; r < 4; ++r)
        C[(rowb + r) * N + col] = acc[mi][ni][r];
    }
}

// ---------------------------------------------------------------------------
// MFMA flash attention. One wave per (b, h, 16-query block).
// ---------------------------------------------------------------------------
__global__ __launch_bounds__(256) void attn_kernel(
    const unsigned short* __restrict__ qb,   // [BS][1024]
    const unsigned short* __restrict__ kb,   // [BS][256]
    const unsigned short* __restrict__ vt,   // [B*KVH][64][S]
    unsigned short* __restrict__ ao) {       // [BS][1024]
  __shared__ __align__(16) unsigned short plds[4][16][104];
  const int w = threadIdx.x >> 6, lane = threadIdx.x & 63;
  const int lrow = lane & 15, quad = lane >> 4;
  const int wg = blockIdx.x * 4 + w;
  const int h = wg & (H - 1);
  const int qblk = wg >> 4;
  const int i0 = (qblk & (S / 16 - 1)) * 16;
  const int b = qblk >> 7;
  const int kvh = h >> 2;
  const int jbase = i0 - 80;

  const unsigned short* qrow = qb + (size_t)(b * S + i0 + lrow) * 1024 + h * 64 + quad * 8;
  short8 qf0 = *(const short8*)qrow;
  short8 qf1 = *(const short8*)(qrow + 32);

  floatx4 sc[6];
#pragma unroll
  for (int t = 0; t < 6; ++t) {
    int j = jbase + t * 16 + lrow;
    int jc = j < 0 ? 0 : j;
    const unsigned short* krow = kb + (size_t)(b * S + jc) * 256 + kvh * 64 + quad * 8;
    short8 kf0 = *(const short8*)krow;
    short8 kf1 = *(const short8*)(krow + 32);
    floatx4 a = {0.f, 0.f, 0.f, 0.f};
    a = __builtin_amdgcn_mfma_f32_16x16x32_bf16(qf0, kf0, a, 0, 0, 0);
    a = __builtin_amdgcn_mfma_f32_16x16x32_bf16(qf1, kf1, a, 0, 0, 0);
    sc[t] = a;
  }

  float sv[6][4];
  float mx[4] = {-1e30f, -1e30f, -1e30f, -1e30f};
#pragma unroll
  for (int t = 0; t < 6; ++t) {
    int j = jbase + t * 16 + lrow;
#pragma unroll
    for (int r = 0; r < 4; ++r) {
      int dji = (i0 + quad * 4 + r) - j;
      bool valid = (j >= 0) && (dji >= 0) && (dji <= 64);
      float s = valid ? sc[t][r] * 0.125f : -1e30f;
      sv[t][r] = s;
      mx[r] = fmaxf(mx[r], s);
    }
  }
#pragma unroll
  for (int r = 0; r < 4; ++r)
#pragma unroll
    for (int off = 8; off > 0; off >>= 1)
      mx[r] = fmaxf(mx[r], __shfl_xor(mx[r], off));

  float ls[4] = {0.f, 0.f, 0.f, 0.f};
#pragma unroll
  for (int t = 0; t < 6; ++t)
#pragma unroll
    for (int r = 0; r < 4; ++r) {
      float e = __expf(sv[t][r] - mx[r]);
      sv[t][r] = e;
      ls[r] += e;
    }
#pragma unroll
  for (int r = 0; r < 4; ++r) {
#pragma unroll
    for (int off = 8; off > 0; off >>= 1)
      ls[r] += __shfl_xor(ls[r], off);
    ls[r] = 1.f / ls[r];
  }
#pragma unroll
  for (int t = 0; t < 6; ++t)
#pragma unroll
    for (int r = 0; r < 4; ++r)
      plds[w][quad * 4 + r][t * 16 + lrow] = f2bf(sv[t][r] * ls[r]);
  __syncthreads();

  floatx4 oc[4];
#pragma unroll
  for (int mt = 0; mt < 4; ++mt) oc[mt] = floatx4{0.f, 0.f, 0.f, 0.f};
  const unsigned short* vbase = vt + (size_t)(b * KVH + kvh) * 64 * S;
#pragma unroll
  for (int c = 0; c < 3; ++c) {
    short8 pf = *(const short8*)&plds[w][lrow][c * 32 + quad * 8];
    int j = jbase + c * 32 + quad * 8;
    int jc = j < 0 ? 0 : j;
#pragma unroll
    for (int mt = 0; mt < 4; ++mt) {
      short8 vf = *(const short8*)(vbase + (size_t)(mt * 16 + lrow) * S + jc);
      oc[mt] = __builtin_amdgcn_mfma_f32_16x16x32_bf16(vf, pf, oc[mt], 0, 0, 0);
    }
  }

#pragma unroll
  for (int mt = 0; mt < 4; ++mt) {
    ushort4 o;
    o.x = f2bf(oc[mt][0]); o.y = f2bf(oc[mt][1]);
    o.z = f2bf(oc[mt][2]); o.w = f2bf(oc[mt][3]);
    *(ushort4*)(ao + (size_t)(b * S + i0 + lrow) * 1024 + h * 64 + mt * 16 + quad * 4) = o;
  }
}

// ---------------------------------------------------------------------------
extern "C" void kernel_launch(void* const* d_in, const int* in_sizes, int n_in,
                              void* d_out, int out_size, void* d_ws, size_t ws_size,
                              hipStream_t stream) {
  const float* x  = (const float*)d_in[0];
  const float* fc = (const float*)d_in[1];
  const float* fs = (const float*)d_in[2];
  const float* wq = (const float*)d_in[3];
  const float* wk = (const float*)d_in[4];
  const float* wv = (const float*)d_in[5];
  const float* wo = (const float*)d_in[6];
  float* out = (float*)d_out;

  // ws: [xb 8M][wqkvT 3M][woT 2M][qb 8M][kb 2M][vT 2M][ao 8M] = 33 MiB
  char* base = (char*)d_ws;
  unsigned short* xb    = (unsigned short*)base;
  unsigned short* wqkvT = (unsigned short*)(base + (8u << 20));
  unsigned short* woT   = (unsigned short*)(base + (11u << 20));
  unsigned short* qb    = (unsigned short*)(base + (13u << 20));
  unsigned short* kb    = (unsigned short*)(base + (21u << 20));
  unsigned short* vT    = (unsigned short*)(base + (23u << 20));
  unsigned short* ao    = (unsigned short*)(base + (25u << 20));

  // 1) prep: cast x + transpose all weights
  prep_kernel<<<4096 + 2560, 256, 0, stream>>>(x, wq, wk, wv, wo, xb, wqkvT, woT);

  // 2) fused QKV GEMM + RoPE + V-transpose
  gemm_qkv_kernel<<<dim3(QS / 128, BS / 128), 256, 0, stream>>>(
      xb, wqkvT, fc, fs, qb, kb, vT);

  // 3) MFMA attention -> ao bf16 [4096,1024]
  attn_kernel<<<(BS / 16) * H / 4, 256, 0, stream>>>(qb, kb, vT, ao);

  // 4) output projection -> fp32
  gemm_bt_kernel<<<dim3(D / 128, BS / 128), 256, 0, stream>>>(ao, woT, out, D, D);
}

// Round 6
// 142.307 us; speedup vs baseline: 5.2781x; 1.0872x over previous
//
#include <hip/hip_runtime.h>
#include <hip/hip_bf16.h>

constexpr int B = 2, S = 2048, D = 1024;
constexpr int H = 16, KVH = 4, HD = 64;
constexpr int BS = B * S;                 // 4096
constexpr int QS = 1536;                  // fused qkv width

typedef __attribute__((ext_vector_type(8))) short short8;
typedef __attribute__((ext_vector_type(4))) float floatx4;

#define GPTR(p) ((__attribute__((address_space(1))) void*)(p))
#define LPTR(p) ((__attribute__((address_space(3))) void*)(p))

static __device__ __forceinline__ unsigned short f2bf(float f) {
  union { float f; unsigned u; } c{f};
  unsigned r = (c.u + 0x7FFFu + ((c.u >> 16) & 1u)) >> 16;
  return (unsigned short)r;
}

// ---------------------------------------------------------------------------
// Prep: x fp32 -> bf16 (blocks [0,4096)) and all 4 weight transposes
// (blocks [4096, 4096+2560)). fp32 [K=1024,N] -> bf16 [N,1024].
// ---------------------------------------------------------------------------
__global__ __launch_bounds__(256) void prep_kernel(
    const float* __restrict__ x,
    const float* __restrict__ wq, const float* __restrict__ wk,
    const float* __restrict__ wv, const float* __restrict__ wo,
    unsigned short* __restrict__ xb,
    unsigned short* __restrict__ wqkvT, unsigned short* __restrict__ woT) {
  int bz = blockIdx.x;
  if (bz < 4096) {
    int t = bz * 256 + threadIdx.x;
    float4 v = ((const float4*)x)[t];
    ushort4 o;
    o.x = f2bf(v.x); o.y = f2bf(v.y); o.z = f2bf(v.z); o.w = f2bf(v.w);
    ((ushort4*)xb)[t] = o;
    return;
  }
  __shared__ float t[32][33];
  int z = bz - 4096;                 // 0..2559
  int zx = z % 80, zy = z / 80;      // region-select, k-block
  const float* src; unsigned short* dst; int N, dstOff, nb;
  if (zx < 32)      { src = wq; dst = wqkvT; N = 1024; dstOff = 0;    nb = zx; }
  else if (zx < 40) { src = wk; dst = wqkvT; N = 256;  dstOff = 1024; nb = zx - 32; }
  else if (zx < 48) { src = wv; dst = wqkvT; N = 256;  dstOff = 1280; nb = zx - 40; }
  else              { src = wo; dst = woT;   N = 1024; dstOff = 0;    nb = zx - 48; }
  int n0 = nb * 32, k0 = zy * 32;
  int tx = threadIdx.x & 31, ty = threadIdx.x >> 5;
#pragma unroll
  for (int r = 0; r < 4; ++r)
    t[ty + r * 8][tx] = src[(size_t)(k0 + ty + r * 8) * N + n0 + tx];
  __syncthreads();
#pragma unroll
  for (int r = 0; r < 4; ++r)
    dst[(size_t)(dstOff + n0 + ty + r * 8) * D + k0 + tx] = f2bf(t[tx][ty + r * 8]);
}

// ---------------------------------------------------------------------------
// Shared GEMM K-loop macro pieces: 128x64 tile, BK=64 (two 32-k halves, each
// in the m97 linear [row][32] LDS layout), K=1024 fixed.
// Wave grid 2x2: wave = 64 rows x 32 cols, 4x2 frags, 16 MFMA per kstep.
// ---------------------------------------------------------------------------
#define GEMM_PROLOGUE(Aptr, Btptr)                                            \
  __shared__ unsigned short As[2 * 128 * 32];                                 \
  __shared__ unsigned short Bs[2 * 64 * 32];                                  \
  const int tid = threadIdx.x;                                                \
  const int lane = tid & 63, wvid = tid >> 6;                                 \
  const int wy = wvid >> 1, wx = wvid & 1;                                    \
  const int quad = lane >> 4, lrow = lane & 15;                               \
  const size_t row0 = (size_t)blockIdx.y * 128;                               \
  const size_t col0 = (size_t)blockIdx.x * 64;                                \
  floatx4 acc[4][2];                                                          \
  _Pragma("unroll") for (int i = 0; i < 4; ++i)                               \
    _Pragma("unroll") for (int j = 0; j < 2; ++j)                             \
      acc[i][j] = floatx4{0.f, 0.f, 0.f, 0.f};                                \
  const int arow = wvid * 32 + (lane >> 2);                                   \
  const int brow = wvid * 16 + (lane >> 2);                                   \
  const int schk = (lane & 3) * 8;                                            \
  const unsigned short* gA = (Aptr) + (row0 + arow) * 1024 + schk;            \
  const unsigned short* gB = (Btptr) + (col0 + brow) * 1024 + schk;           \
  char* ldsA = (char*)As + wvid * 2048;                                       \
  char* ldsB = (char*)Bs + wvid * 1024;                                       \
  for (int k0 = 0; k0 < 1024; k0 += 64) {                                     \
    __syncthreads();                                                          \
    __builtin_amdgcn_global_load_lds(GPTR(gA + k0), LPTR(ldsA), 16, 0, 0);    \
    __builtin_amdgcn_global_load_lds(GPTR(gA + 16 * 1024 + k0),               \
                                     LPTR(ldsA + 1024), 16, 0, 0);            \
    __builtin_amdgcn_global_load_lds(GPTR(gB + k0), LPTR(ldsB), 16, 0, 0);    \
    __builtin_amdgcn_global_load_lds(GPTR(gA + k0 + 32), LPTR(ldsA + 8192),   \
                                     16, 0, 0);                               \
    __builtin_amdgcn_global_load_lds(GPTR(gA + 16 * 1024 + k0 + 32),          \
                                     LPTR(ldsA + 8192 + 1024), 16, 0, 0);     \
    __builtin_amdgcn_global_load_lds(GPTR(gB + k0 + 32), LPTR(ldsB + 4096),   \
                                     16, 0, 0);                               \
    __syncthreads();                                                          \
    _Pragma("unroll") for (int hf = 0; hf < 2; ++hf) {                        \
      short8 af[4], bg[2];                                                    \
      _Pragma("unroll") for (int mi = 0; mi < 4; ++mi)                        \
        af[mi] = *(const short8*)&As[hf * 4096 +                              \
                                     (wy * 64 + mi * 16 + lrow) * 32 + quad * 8]; \
      _Pragma("unroll") for (int ni = 0; ni < 2; ++ni)                        \
        bg[ni] = *(const short8*)&Bs[hf * 2048 +                              \
                                     (wx * 32 + ni * 16 + lrow) * 32 + quad * 8]; \
      _Pragma("unroll") for (int mi = 0; mi < 4; ++mi)                        \
        _Pragma("unroll") for (int ni = 0; ni < 2; ++ni)                      \
          acc[mi][ni] = __builtin_amdgcn_mfma_f32_16x16x32_bf16(              \
              af[mi], bg[ni], acc[mi][ni], 0, 0, 0);                          \
    }                                                                         \
  }

// ---------------------------------------------------------------------------
// Fused QKV GEMM + RoPE + V-transpose.  C[4096,1536] never materialized.
// Wave col span = 32, inside one 64-wide head -> q/k/v branch wave-uniform.
//  - q heads (col<1024):  RoPE on fp32 acc -> qb [BS,1024]
//  - k heads (1024..1280): RoPE -> kb [BS,256]
//  - v heads (1280..1536): transposed store -> vT [B*KVH][64][S]
// RoPE pair partner lives in lane^1 (col parity = lrow parity).
// ---------------------------------------------------------------------------
__global__ __launch_bounds__(256) void gemm_qkv_kernel(
    const unsigned short* __restrict__ A, const unsigned short* __restrict__ Bt,
    const float* __restrict__ cs, const float* __restrict__ sn,
    unsigned short* __restrict__ qb, unsigned short* __restrict__ kb,
    unsigned short* __restrict__ vt) {
  GEMM_PROLOGUE(A, Bt)

  const int col_wave = (int)col0 + wx * 32;     // wave-uniform, within one head
  const int h = col_wave >> 6;
  const int hc = col_wave & 63;                 // 0 or 32 within the head
  const int sb = (int)(row0 & 2047) + wy * 64;  // seq base for this wave
  const int bidx = (int)(row0 >> 11);           // batch (tile never straddles)

  if (h < 20) {
    unsigned short* dst = (h < 16) ? qb : kb;
    const int dstride = (h < 16) ? 1024 : 256;
    const int dcol = (h < 16) ? col_wave : (col_wave - 1024);
    const bool ev = (lrow & 1) == 0;
#pragma unroll
    for (int mi = 0; mi < 4; ++mi) {
#pragma unroll
      for (int ni = 0; ni < 2; ++ni) {
        int ff = (hc + ni * 16 + lrow) >> 1;
#pragma unroll
        for (int r = 0; r < 4; ++r) {
          int s = sb + mi * 16 + quad * 4 + r;
          float v = acc[mi][ni][r];
          float p = __shfl_xor(v, 1);
          float c = cs[s * 32 + ff];
          float si = sn[s * 32 + ff];
          float o = ev ? (v * c - p * si) : (v * c + p * si);
          size_t row = row0 + wy * 64 + mi * 16 + quad * 4 + r;
          dst[row * dstride + dcol + ni * 16 + lrow] = f2bf(o);
        }
      }
    }
  } else {
    const int kvh = h - 20;
    const int g = bidx * KVH + kvh;
#pragma unroll
    for (int mi = 0; mi < 4; ++mi) {
#pragma unroll
      for (int ni = 0; ni < 2; ++ni) {
        int d = hc + ni * 16 + lrow;
        int s0 = sb + mi * 16 + quad * 4;
        ushort4 o;
        o.x = f2bf(acc[mi][ni][0]); o.y = f2bf(acc[mi][ni][1]);
        o.z = f2bf(acc[mi][ni][2]); o.w = f2bf(acc[mi][ni][3]);
        *(ushort4*)&vt[((size_t)(g * 64 + d)) * S + s0] = o;
      }
    }
  }
}

// ---------------------------------------------------------------------------
// Output projection GEMM -> fp32 C. Same 128x64 / BK=64 structure.
// ---------------------------------------------------------------------------
__global__ __launch_bounds__(256) void gemm_bt_kernel(
    const unsigned short* __restrict__ A, const unsigned short* __restrict__ Bt,
    float* __restrict__ C, int N) {
  GEMM_PROLOGUE(A, Bt)

#pragma unroll
  for (int mi = 0; mi < 4; ++mi)
#pragma unroll
    for (int ni = 0; ni < 2; ++ni) {
      size_t col = col0 + wx * 32 + ni * 16 + lrow;
      size_t rowb = row0 + wy * 64 + mi * 16 + quad * 4;
#pragma unroll
      for (int r = 0; r < 4; ++r)
        C[(rowb + r) * N + col] = acc[mi][ni][r];
    }
}

// ---------------------------------------------------------------------------
// MFMA flash attention. One wave per (b, h, 16-query block).
// ---------------------------------------------------------------------------
__global__ __launch_bounds__(256) void attn_kernel(
    const unsigned short* __restrict__ qb,   // [BS][1024]
    const unsigned short* __restrict__ kb,   // [BS][256]
    const unsigned short* __restrict__ vt,   // [B*KVH][64][S]
    unsigned short* __restrict__ ao) {       // [BS][1024]
  __shared__ __align__(16) unsigned short plds[4][16][104];
  const int w = threadIdx.x >> 6, lane = threadIdx.x & 63;
  const int lrow = lane & 15, quad = lane >> 4;
  const int wg = blockIdx.x * 4 + w;
  const int h = wg & (H - 1);
  const int qblk = wg >> 4;
  const int i0 = (qblk & (S / 16 - 1)) * 16;
  const int b = qblk >> 7;
  const int kvh = h >> 2;
  const int jbase = i0 - 80;

  const unsigned short* qrow = qb + (size_t)(b * S + i0 + lrow) * 1024 + h * 64 + quad * 8;
  short8 qf0 = *(const short8*)qrow;
  short8 qf1 = *(const short8*)(qrow + 32);

  floatx4 sc[6];
#pragma unroll
  for (int t = 0; t < 6; ++t) {
    int j = jbase + t * 16 + lrow;
    int jc = j < 0 ? 0 : j;
    const unsigned short* krow = kb + (size_t)(b * S + jc) * 256 + kvh * 64 + quad * 8;
    short8 kf0 = *(const short8*)krow;
    short8 kf1 = *(const short8*)(krow + 32);
    floatx4 a = {0.f, 0.f, 0.f, 0.f};
    a = __builtin_amdgcn_mfma_f32_16x16x32_bf16(qf0, kf0, a, 0, 0, 0);
    a = __builtin_amdgcn_mfma_f32_16x16x32_bf16(qf1, kf1, a, 0, 0, 0);
    sc[t] = a;
  }

  float sv[6][4];
  float mx[4] = {-1e30f, -1e30f, -1e30f, -1e30f};
#pragma unroll
  for (int t = 0; t < 6; ++t) {
    int j = jbase + t * 16 + lrow;
#pragma unroll
    for (int r = 0; r < 4; ++r) {
      int dji = (i0 + quad * 4 + r) - j;
      bool valid = (j >= 0) && (dji >= 0) && (dji <= 64);
      float s = valid ? sc[t][r] * 0.125f : -1e30f;
      sv[t][r] = s;
      mx[r] = fmaxf(mx[r], s);
    }
  }
#pragma unroll
  for (int r = 0; r < 4; ++r)
#pragma unroll
    for (int off = 8; off > 0; off >>= 1)
      mx[r] = fmaxf(mx[r], __shfl_xor(mx[r], off));

  float ls[4] = {0.f, 0.f, 0.f, 0.f};
#pragma unroll
  for (int t = 0; t < 6; ++t)
#pragma unroll
    for (int r = 0; r < 4; ++r) {
      float e = __expf(sv[t][r] - mx[r]);
      sv[t][r] = e;
      ls[r] += e;
    }
#pragma unroll
  for (int r = 0; r < 4; ++r) {
#pragma unroll
    for (int off = 8; off > 0; off >>= 1)
      ls[r] += __shfl_xor(ls[r], off);
    ls[r] = 1.f / ls[r];
  }
#pragma unroll
  for (int t = 0; t < 6; ++t)
#pragma unroll
    for (int r = 0; r < 4; ++r)
      plds[w][quad * 4 + r][t * 16 + lrow] = f2bf(sv[t][r] * ls[r]);
  __syncthreads();

  floatx4 oc[4];
#pragma unroll
  for (int mt = 0; mt < 4; ++mt) oc[mt] = floatx4{0.f, 0.f, 0.f, 0.f};
  const unsigned short* vbase = vt + (size_t)(b * KVH + kvh) * 64 * S;
#pragma unroll
  for (int c = 0; c < 3; ++c) {
    short8 pf = *(const short8*)&plds[w][lrow][c * 32 + quad * 8];
    int j = jbase + c * 32 + quad * 8;
    int jc = j < 0 ? 0 : j;
#pragma unroll
    for (int mt = 0; mt < 4; ++mt) {
      short8 vf = *(const short8*)(vbase + (size_t)(mt * 16 + lrow) * S + jc);
      oc[mt] = __builtin_amdgcn_mfma_f32_16x16x32_bf16(vf, pf, oc[mt], 0, 0, 0);
    }
  }

#pragma unroll
  for (int mt = 0; mt < 4; ++mt) {
    ushort4 o;
    o.x = f2bf(oc[mt][0]); o.y = f2bf(oc[mt][1]);
    o.z = f2bf(oc[mt][2]); o.w = f2bf(oc[mt][3]);
    *(ushort4*)(ao + (size_t)(b * S + i0 + lrow) * 1024 + h * 64 + mt * 16 + quad * 4) = o;
  }
}

// ---------------------------------------------------------------------------
extern "C" void kernel_launch(void* const* d_in, const int* in_sizes, int n_in,
                              void* d_out, int out_size, void* d_ws, size_t ws_size,
                              hipStream_t stream) {
  const float* x  = (const float*)d_in[0];
  const float* fc = (const float*)d_in[1];
  const float* fs = (const float*)d_in[2];
  const float* wq = (const float*)d_in[3];
  const float* wk = (const float*)d_in[4];
  const float* wv = (const float*)d_in[5];
  const float* wo = (const float*)d_in[6];
  float* out = (float*)d_out;

  // ws: [xb 8M][wqkvT 3M][woT 2M][qb 8M][kb 2M][vT 2M][ao 8M] = 33 MiB
  char* base = (char*)d_ws;
  unsigned short* xb    = (unsigned short*)base;
  unsigned short* wqkvT = (unsigned short*)(base + (8u << 20));
  unsigned short* woT   = (unsigned short*)(base + (11u << 20));
  unsigned short* qb    = (unsigned short*)(base + (13u << 20));
  unsigned short* kb    = (unsigned short*)(base + (21u << 20));
  unsigned short* vT    = (unsigned short*)(base + (23u << 20));
  unsigned short* ao    = (unsigned short*)(base + (25u << 20));

  // 1) prep: cast x + transpose all weights
  prep_kernel<<<4096 + 2560, 256, 0, stream>>>(x, wq, wk, wv, wo, xb, wqkvT, woT);

  // 2) fused QKV GEMM + RoPE + V-transpose  (768 blocks = 3/CU)
  gemm_qkv_kernel<<<dim3(QS / 64, BS / 128), 256, 0, stream>>>(
      xb, wqkvT, fc, fs, qb, kb, vT);

  // 3) MFMA attention -> ao bf16 [4096,1024]
  attn_kernel<<<(BS / 16) * H / 4, 256, 0, stream>>>(qb, kb, vT, ao);

  // 4) output projection -> fp32  (512 blocks = 2/CU)
  gemm_bt_kernel<<<dim3(D / 64, BS / 128), 256, 0, stream>>>(ao, woT, out, D);
}

// Round 7
// 141.513 us; speedup vs baseline: 5.3077x; 1.0056x over previous
//
#include <hip/hip_runtime.h>
#include <hip/hip_bf16.h>

constexpr int B = 2, S = 2048, D = 1024;
constexpr int H = 16, KVH = 4, HD = 64;
constexpr int BS = B * S;                 // 4096
constexpr int QS = 1536;                  // fused qkv width

typedef __attribute__((ext_vector_type(8))) short short8;
typedef __attribute__((ext_vector_type(4))) float floatx4;

#define GPTR(p) ((__attribute__((address_space(1))) void*)(p))
#define LPTR(p) ((__attribute__((address_space(3))) void*)(p))

static __device__ __forceinline__ unsigned short f2bf(float f) {
  union { float f; unsigned u; } c{f};
  unsigned r = (c.u + 0x7FFFu + ((c.u >> 16) & 1u)) >> 16;
  return (unsigned short)r;
}

// ---------------------------------------------------------------------------
// Prep: x fp32 -> bf16 (blocks [0,4096)) and all 4 weight transposes
// (blocks [4096, 4096+2560)). fp32 [K=1024,N] -> bf16 [N,1024].
// ---------------------------------------------------------------------------
__global__ __launch_bounds__(256) void prep_kernel(
    const float* __restrict__ x,
    const float* __restrict__ wq, const float* __restrict__ wk,
    const float* __restrict__ wv, const float* __restrict__ wo,
    unsigned short* __restrict__ xb,
    unsigned short* __restrict__ wqkvT, unsigned short* __restrict__ woT) {
  int bz = blockIdx.x;
  if (bz < 4096) {
    int t = bz * 256 + threadIdx.x;
    float4 v = ((const float4*)x)[t];
    ushort4 o;
    o.x = f2bf(v.x); o.y = f2bf(v.y); o.z = f2bf(v.z); o.w = f2bf(v.w);
    ((ushort4*)xb)[t] = o;
    return;
  }
  __shared__ float t[32][33];
  int z = bz - 4096;                 // 0..2559
  int zx = z % 80, zy = z / 80;      // region-select, k-block
  const float* src; unsigned short* dst; int N, dstOff, nb;
  if (zx < 32)      { src = wq; dst = wqkvT; N = 1024; dstOff = 0;    nb = zx; }
  else if (zx < 40) { src = wk; dst = wqkvT; N = 256;  dstOff = 1024; nb = zx - 32; }
  else if (zx < 48) { src = wv; dst = wqkvT; N = 256;  dstOff = 1280; nb = zx - 40; }
  else              { src = wo; dst = woT;   N = 1024; dstOff = 0;    nb = zx - 48; }
  int n0 = nb * 32, k0 = zy * 32;
  int tx = threadIdx.x & 31, ty = threadIdx.x >> 5;
#pragma unroll
  for (int r = 0; r < 4; ++r)
    t[ty + r * 8][tx] = src[(size_t)(k0 + ty + r * 8) * N + n0 + tx];
  __syncthreads();
#pragma unroll
  for (int r = 0; r < 4; ++r)
    dst[(size_t)(dstOff + n0 + ty + r * 8) * D + k0 + tx] = f2bf(t[tx][ty + r * 8]);
}

// ---------------------------------------------------------------------------
// Shared GEMM K-loop: 128x64 tile, BK=128 (four 32-k sections, each in the
// m97 linear [row][32] LDS layout), K=1024 fixed -> 8 barrier-pairs.
// Wave grid 2x2: wave = 64 rows x 32 cols, 4x2 frags, 32 MFMA per kstep.
// LDS: As 32 KB + Bs 16 KB = 48 KB -> 3 blocks/CU.
// ---------------------------------------------------------------------------
#define GEMM_PROLOGUE(Aptr, Btptr)                                            \
  __shared__ unsigned short As[4 * 128 * 32];                                 \
  __shared__ unsigned short Bs[4 * 64 * 32];                                  \
  const int tid = threadIdx.x;                                                \
  const int lane = tid & 63, wvid = tid >> 6;                                 \
  const int wy = wvid >> 1, wx = wvid & 1;                                    \
  const int quad = lane >> 4, lrow = lane & 15;                               \
  const size_t row0 = (size_t)blockIdx.y * 128;                               \
  const size_t col0 = (size_t)blockIdx.x * 64;                                \
  floatx4 acc[4][2];                                                          \
  _Pragma("unroll") for (int i = 0; i < 4; ++i)                               \
    _Pragma("unroll") for (int j = 0; j < 2; ++j)                             \
      acc[i][j] = floatx4{0.f, 0.f, 0.f, 0.f};                                \
  const int arow = wvid * 32 + (lane >> 2);                                   \
  const int brow = wvid * 16 + (lane >> 2);                                   \
  const int schk = (lane & 3) * 8;                                            \
  const unsigned short* gA = (Aptr) + (row0 + arow) * 1024 + schk;            \
  const unsigned short* gB = (Btptr) + (col0 + brow) * 1024 + schk;           \
  char* ldsA = (char*)As + wvid * 2048;                                       \
  char* ldsB = (char*)Bs + wvid * 1024;                                       \
  for (int k0 = 0; k0 < 1024; k0 += 128) {                                    \
    __syncthreads();                                                          \
    _Pragma("unroll") for (int hf = 0; hf < 4; ++hf) {                        \
      __builtin_amdgcn_global_load_lds(GPTR(gA + k0 + hf * 32),               \
                                       LPTR(ldsA + hf * 8192), 16, 0, 0);     \
      __builtin_amdgcn_global_load_lds(GPTR(gA + 16 * 1024 + k0 + hf * 32),   \
                                       LPTR(ldsA + hf * 8192 + 1024), 16, 0, 0); \
      __builtin_amdgcn_global_load_lds(GPTR(gB + k0 + hf * 32),               \
                                       LPTR(ldsB + hf * 4096), 16, 0, 0);     \
    }                                                                         \
    __syncthreads();                                                          \
    _Pragma("unroll") for (int hf = 0; hf < 4; ++hf) {                        \
      short8 af[4], bg[2];                                                    \
      _Pragma("unroll") for (int mi = 0; mi < 4; ++mi)                        \
        af[mi] = *(const short8*)&As[hf * 4096 +                              \
                                     (wy * 64 + mi * 16 + lrow) * 32 + quad * 8]; \
      _Pragma("unroll") for (int ni = 0; ni < 2; ++ni)                        \
        bg[ni] = *(const short8*)&Bs[hf * 2048 +                              \
                                     (wx * 32 + ni * 16 + lrow) * 32 + quad * 8]; \
      _Pragma("unroll") for (int mi = 0; mi < 4; ++mi)                        \
        _Pragma("unroll") for (int ni = 0; ni < 2; ++ni)                      \
          acc[mi][ni] = __builtin_amdgcn_mfma_f32_16x16x32_bf16(              \
              af[mi], bg[ni], acc[mi][ni], 0, 0, 0);                          \
    }                                                                         \
  }

// ---------------------------------------------------------------------------
// Fused QKV GEMM + RoPE + V-transpose.  C[4096,1536] never materialized.
// Wave col span = 32, inside one 64-wide head -> q/k/v branch wave-uniform.
// ---------------------------------------------------------------------------
__global__ __launch_bounds__(256) void gemm_qkv_kernel(
    const unsigned short* __restrict__ A, const unsigned short* __restrict__ Bt,
    const float* __restrict__ cs, const float* __restrict__ sn,
    unsigned short* __restrict__ qb, unsigned short* __restrict__ kb,
    unsigned short* __restrict__ vt) {
  GEMM_PROLOGUE(A, Bt)

  const int col_wave = (int)col0 + wx * 32;     // wave-uniform, within one head
  const int h = col_wave >> 6;
  const int hc = col_wave & 63;                 // 0 or 32 within the head
  const int sb = (int)(row0 & 2047) + wy * 64;  // seq base for this wave
  const int bidx = (int)(row0 >> 11);           // batch (tile never straddles)

  if (h < 20) {
    unsigned short* dst = (h < 16) ? qb : kb;
    const int dstride = (h < 16) ? 1024 : 256;
    const int dcol = (h < 16) ? col_wave : (col_wave - 1024);
    const bool ev = (lrow & 1) == 0;
#pragma unroll
    for (int mi = 0; mi < 4; ++mi) {
#pragma unroll
      for (int ni = 0; ni < 2; ++ni) {
        int ff = (hc + ni * 16 + lrow) >> 1;
#pragma unroll
        for (int r = 0; r < 4; ++r) {
          int s = sb + mi * 16 + quad * 4 + r;
          float v = acc[mi][ni][r];
          float p = __shfl_xor(v, 1);
          float c = cs[s * 32 + ff];
          float si = sn[s * 32 + ff];
          float o = ev ? (v * c - p * si) : (v * c + p * si);
          size_t row = row0 + wy * 64 + mi * 16 + quad * 4 + r;
          dst[row * dstride + dcol + ni * 16 + lrow] = f2bf(o);
        }
      }
    }
  } else {
    const int kvh = h - 20;
    const int g = bidx * KVH + kvh;
#pragma unroll
    for (int mi = 0; mi < 4; ++mi) {
#pragma unroll
      for (int ni = 0; ni < 2; ++ni) {
        int d = hc + ni * 16 + lrow;
        int s0 = sb + mi * 16 + quad * 4;
        ushort4 o;
        o.x = f2bf(acc[mi][ni][0]); o.y = f2bf(acc[mi][ni][1]);
        o.z = f2bf(acc[mi][ni][2]); o.w = f2bf(acc[mi][ni][3]);
        *(ushort4*)&vt[((size_t)(g * 64 + d)) * S + s0] = o;
      }
    }
  }
}

// ---------------------------------------------------------------------------
// Output projection GEMM -> fp32 C. Same 128x64 / BK=128 structure.
// ---------------------------------------------------------------------------
__global__ __launch_bounds__(256) void gemm_bt_kernel(
    const unsigned short* __restrict__ A, const unsigned short* __restrict__ Bt,
    float* __restrict__ C, int N) {
  GEMM_PROLOGUE(A, Bt)

#pragma unroll
  for (int mi = 0; mi < 4; ++mi)
#pragma unroll
    for (int ni = 0; ni < 2; ++ni) {
      size_t col = col0 + wx * 32 + ni * 16 + lrow;
      size_t rowb = row0 + wy * 64 + mi * 16 + quad * 4;
#pragma unroll
      for (int r = 0; r < 4; ++r)
        C[(rowb + r) * N + col] = acc[mi][ni][r];
    }
}

// ---------------------------------------------------------------------------
// MFMA flash attention. One wave per (b, h, 16-query block).
// ---------------------------------------------------------------------------
__global__ __launch_bounds__(256) void attn_kernel(
    const unsigned short* __restrict__ qb,   // [BS][1024]
    const unsigned short* __restrict__ kb,   // [BS][256]
    const unsigned short* __restrict__ vt,   // [B*KVH][64][S]
    unsigned short* __restrict__ ao) {       // [BS][1024]
  __shared__ __align__(16) unsigned short plds[4][16][104];
  const int w = threadIdx.x >> 6, lane = threadIdx.x & 63;
  const int lrow = lane & 15, quad = lane >> 4;
  const int wg = blockIdx.x * 4 + w;
  const int h = wg & (H - 1);
  const int qblk = wg >> 4;
  const int i0 = (qblk & (S / 16 - 1)) * 16;
  const int b = qblk >> 7;
  const int kvh = h >> 2;
  const int jbase = i0 - 80;

  const unsigned short* qrow = qb + (size_t)(b * S + i0 + lrow) * 1024 + h * 64 + quad * 8;
  short8 qf0 = *(const short8*)qrow;
  short8 qf1 = *(const short8*)(qrow + 32);

  floatx4 sc[6];
#pragma unroll
  for (int t = 0; t < 6; ++t) {
    int j = jbase + t * 16 + lrow;
    int jc = j < 0 ? 0 : j;
    const unsigned short* krow = kb + (size_t)(b * S + jc) * 256 + kvh * 64 + quad * 8;
    short8 kf0 = *(const short8*)krow;
    short8 kf1 = *(const short8*)(krow + 32);
    floatx4 a = {0.f, 0.f, 0.f, 0.f};
    a = __builtin_amdgcn_mfma_f32_16x16x32_bf16(qf0, kf0, a, 0, 0, 0);
    a = __builtin_amdgcn_mfma_f32_16x16x32_bf16(qf1, kf1, a, 0, 0, 0);
    sc[t] = a;
  }

  float sv[6][4];
  float mx[4] = {-1e30f, -1e30f, -1e30f, -1e30f};
#pragma unroll
  for (int t = 0; t < 6; ++t) {
    int j = jbase + t * 16 + lrow;
#pragma unroll
    for (int r = 0; r < 4; ++r) {
      int dji = (i0 + quad * 4 + r) - j;
      bool valid = (j >= 0) && (dji >= 0) && (dji <= 64);
      float s = valid ? sc[t][r] * 0.125f : -1e30f;
      sv[t][r] = s;
      mx[r] = fmaxf(mx[r], s);
    }
  }
#pragma unroll
  for (int r = 0; r < 4; ++r)
#pragma unroll
    for (int off = 8; off > 0; off >>= 1)
      mx[r] = fmaxf(mx[r], __shfl_xor(mx[r], off));

  float ls[4] = {0.f, 0.f, 0.f, 0.f};
#pragma unroll
  for (int t = 0; t < 6; ++t)
#pragma unroll
    for (int r = 0; r < 4; ++r) {
      float e = __expf(sv[t][r] - mx[r]);
      sv[t][r] = e;
      ls[r] += e;
    }
#pragma unroll
  for (int r = 0; r < 4; ++r) {
#pragma unroll
    for (int off = 8; off > 0; off >>= 1)
      ls[r] += __shfl_xor(ls[r], off);
    ls[r] = 1.f / ls[r];
  }
#pragma unroll
  for (int t = 0; t < 6; ++t)
#pragma unroll
    for (int r = 0; r < 4; ++r)
      plds[w][quad * 4 + r][t * 16 + lrow] = f2bf(sv[t][r] * ls[r]);
  __syncthreads();

  floatx4 oc[4];
#pragma unroll
  for (int mt = 0; mt < 4; ++mt) oc[mt] = floatx4{0.f, 0.f, 0.f, 0.f};
  const unsigned short* vbase = vt + (size_t)(b * KVH + kvh) * 64 * S;
#pragma unroll
  for (int c = 0; c < 3; ++c) {
    short8 pf = *(const short8*)&plds[w][lrow][c * 32 + quad * 8];
    int j = jbase + c * 32 + quad * 8;
    int jc = j < 0 ? 0 : j;
#pragma unroll
    for (int mt = 0; mt < 4; ++mt) {
      short8 vf = *(const short8*)(vbase + (size_t)(mt * 16 + lrow) * S + jc);
      oc[mt] = __builtin_amdgcn_mfma_f32_16x16x32_bf16(vf, pf, oc[mt], 0, 0, 0);
    }
  }

#pragma unroll
  for (int mt = 0; mt < 4; ++mt) {
    ushort4 o;
    o.x = f2bf(oc[mt][0]); o.y = f2bf(oc[mt][1]);
    o.z = f2bf(oc[mt][2]); o.w = f2bf(oc[mt][3]);
    *(ushort4*)(ao + (size_t)(b * S + i0 + lrow) * 1024 + h * 64 + mt * 16 + quad * 4) = o;
  }
}

// ---------------------------------------------------------------------------
extern "C" void kernel_launch(void* const* d_in, const int* in_sizes, int n_in,
                              void* d_out, int out_size, void* d_ws, size_t ws_size,
                              hipStream_t stream) {
  const float* x  = (const float*)d_in[0];
  const float* fc = (const float*)d_in[1];
  const float* fs = (const float*)d_in[2];
  const float* wq = (const float*)d_in[3];
  const float* wk = (const float*)d_in[4];
  const float* wv = (const float*)d_in[5];
  const float* wo = (const float*)d_in[6];
  float* out = (float*)d_out;

  // ws: [xb 8M][wqkvT 3M][woT 2M][qb 8M][kb 2M][vT 2M][ao 8M] = 33 MiB
  char* base = (char*)d_ws;
  unsigned short* xb    = (unsigned short*)base;
  unsigned short* wqkvT = (unsigned short*)(base + (8u << 20));
  unsigned short* woT   = (unsigned short*)(base + (11u << 20));
  unsigned short* qb    = (unsigned short*)(base + (13u << 20));
  unsigned short* kb    = (unsigned short*)(base + (21u << 20));
  unsigned short* vT    = (unsigned short*)(base + (23u << 20));
  unsigned short* ao    = (unsigned short*)(base + (25u << 20));

  // 1) prep: cast x + transpose all weights
  prep_kernel<<<4096 + 2560, 256, 0, stream>>>(x, wq, wk, wv, wo, xb, wqkvT, woT);

  // 2) fused QKV GEMM + RoPE + V-transpose  (768 blocks = 3/CU)
  gemm_qkv_kernel<<<dim3(QS / 64, BS / 128), 256, 0, stream>>>(
      xb, wqkvT, fc, fs, qb, kb, vT);

  // 3) MFMA attention -> ao bf16 [4096,1024]
  attn_kernel<<<(BS / 16) * H / 4, 256, 0, stream>>>(qb, kb, vT, ao);

  // 4) output projection -> fp32  (512 blocks = 2/CU)
  gemm_bt_kernel<<<dim3(D / 64, BS / 128), 256, 0, stream>>>(ao, woT, out, D);
}

// Round 9
// 139.654 us; speedup vs baseline: 5.3784x; 1.0133x over previous
//
#include <hip/hip_runtime.h>
#include <hip/hip_bf16.h>

constexpr int B = 2, S = 2048, D = 1024;
constexpr int H = 16, KVH = 4, HD = 64;
constexpr int BS = B * S;                 // 4096
constexpr int QS = 1536;                  // fused qkv width

typedef __attribute__((ext_vector_type(8))) short short8;
typedef __attribute__((ext_vector_type(4))) float floatx4;

#define GPTR(p) ((__attribute__((address_space(1))) void*)(p))
#define LPTR(p) ((__attribute__((address_space(3))) void*)(p))

static __device__ __forceinline__ unsigned short f2bf(float f) {
  union { float f; unsigned u; } c{f};
  unsigned r = (c.u + 0x7FFFu + ((c.u >> 16) & 1u)) >> 16;
  return (unsigned short)r;
}

// ---------------------------------------------------------------------------
// Prep: x fp32 -> bf16 (blocks [0,4096)) and all 4 weight transposes
// (blocks [4096, 4096+2560)). fp32 [K=1024,N] -> bf16 [N,1024].
// ---------------------------------------------------------------------------
__global__ __launch_bounds__(256) void prep_kernel(
    const float* __restrict__ x,
    const float* __restrict__ wq, const float* __restrict__ wk,
    const float* __restrict__ wv, const float* __restrict__ wo,
    unsigned short* __restrict__ xb,
    unsigned short* __restrict__ wqkvT, unsigned short* __restrict__ woT) {
  int bz = blockIdx.x;
  if (bz < 4096) {
    int t = bz * 256 + threadIdx.x;
    float4 v = ((const float4*)x)[t];
    ushort4 o;
    o.x = f2bf(v.x); o.y = f2bf(v.y); o.z = f2bf(v.z); o.w = f2bf(v.w);
    ((ushort4*)xb)[t] = o;
    return;
  }
  __shared__ float t[32][33];
  int z = bz - 4096;                 // 0..2559
  int zx = z % 80, zy = z / 80;      // region-select, k-block
  const float* src; unsigned short* dst; int N, dstOff, nb;
  if (zx < 32)      { src = wq; dst = wqkvT; N = 1024; dstOff = 0;    nb = zx; }
  else if (zx < 40) { src = wk; dst = wqkvT; N = 256;  dstOff = 1024; nb = zx - 32; }
  else if (zx < 48) { src = wv; dst = wqkvT; N = 256;  dstOff = 1280; nb = zx - 40; }
  else              { src = wo; dst = woT;   N = 1024; dstOff = 0;    nb = zx - 48; }
  int n0 = nb * 32, k0 = zy * 32;
  int tx = threadIdx.x & 31, ty = threadIdx.x >> 5;
#pragma unroll
  for (int r = 0; r < 4; ++r)
    t[ty + r * 8][tx] = src[(size_t)(k0 + ty + r * 8) * N + n0 + tx];
  __syncthreads();
#pragma unroll
  for (int r = 0; r < 4; ++r)
    dst[(size_t)(dstOff + n0 + ty + r * 8) * D + k0 + tx] = f2bf(t[tx][ty + r * 8]);
}

// ---------------------------------------------------------------------------
// Shared GEMM K-loop: 128x64 tile, BK=128 (four 32-k sections, each in the
// m97 linear [row][32] LDS layout), K=1024 fixed -> 8 barrier-pairs.
// Wave grid 2x2: wave = 64 rows x 32 cols, 4x2 frags, 32 MFMA per kstep.
// LDS: As 32 KB + Bs 16 KB = 48 KB -> 3 blocks/CU.
// XCD-aware mapping: blockIdx.x = ROW tile (fast-moving -> id%8 partitions
// A row-blocks across XCDs, ~1 MB A per XCD stays L2-resident; B col-block
// is read once per XCD while hot). blockIdx.y = COL tile.
// ---------------------------------------------------------------------------
#define GEMM_PROLOGUE(Aptr, Btptr)                                            \
  __shared__ unsigned short As[4 * 128 * 32];                                 \
  __shared__ unsigned short Bs[4 * 64 * 32];                                  \
  const int tid = threadIdx.x;                                                \
  const int lane = tid & 63, wvid = tid >> 6;                                 \
  const int wy = wvid >> 1, wx = wvid & 1;                                    \
  const int quad = lane >> 4, lrow = lane & 15;                               \
  const size_t row0 = (size_t)blockIdx.x * 128;                               \
  const size_t col0 = (size_t)blockIdx.y * 64;                                \
  floatx4 acc[4][2];                                                          \
  _Pragma("unroll") for (int i = 0; i < 4; ++i)                               \
    _Pragma("unroll") for (int j = 0; j < 2; ++j)                             \
      acc[i][j] = floatx4{0.f, 0.f, 0.f, 0.f};                                \
  const int arow = wvid * 32 + (lane >> 2);                                   \
  const int brow = wvid * 16 + (lane >> 2);                                   \
  const int schk = (lane & 3) * 8;                                            \
  const unsigned short* gA = (Aptr) + (row0 + arow) * 1024 + schk;            \
  const unsigned short* gB = (Btptr) + (col0 + brow) * 1024 + schk;           \
  char* ldsA = (char*)As + wvid * 2048;                                       \
  char* ldsB = (char*)Bs + wvid * 1024;                                       \
  for (int k0 = 0; k0 < 1024; k0 += 128) {                                    \
    __syncthreads();                                                          \
    _Pragma("unroll") for (int hf = 0; hf < 4; ++hf) {                        \
      __builtin_amdgcn_global_load_lds(GPTR(gA + k0 + hf * 32),               \
                                       LPTR(ldsA + hf * 8192), 16, 0, 0);     \
      __builtin_amdgcn_global_load_lds(GPTR(gA + 16 * 1024 + k0 + hf * 32),   \
                                       LPTR(ldsA + hf * 8192 + 1024), 16, 0, 0); \
      __builtin_amdgcn_global_load_lds(GPTR(gB + k0 + hf * 32),               \
                                       LPTR(ldsB + hf * 4096), 16, 0, 0);     \
    }                                                                         \
    __syncthreads();                                                          \
    _Pragma("unroll") for (int hf = 0; hf < 4; ++hf) {                        \
      short8 af[4], bg[2];                                                    \
      _Pragma("unroll") for (int mi = 0; mi < 4; ++mi)                        \
        af[mi] = *(const short8*)&As[hf * 4096 +                              \
                                     (wy * 64 + mi * 16 + lrow) * 32 + quad * 8]; \
      _Pragma("unroll") for (int ni = 0; ni < 2; ++ni)                        \
        bg[ni] = *(const short8*)&Bs[hf * 2048 +                              \
                                     (wx * 32 + ni * 16 + lrow) * 32 + quad * 8]; \
      _Pragma("unroll") for (int mi = 0; mi < 4; ++mi)                        \
        _Pragma("unroll") for (int ni = 0; ni < 2; ++ni)                      \
          acc[mi][ni] = __builtin_amdgcn_mfma_f32_16x16x32_bf16(              \
              af[mi], bg[ni], acc[mi][ni], 0, 0, 0);                          \
    }                                                                         \
  }

// ---------------------------------------------------------------------------
// Fused QKV GEMM + RoPE + V-transpose.  C[4096,1536] never materialized.
// Wave col span = 32, inside one 64-wide head -> q/k/v branch wave-uniform.
// ---------------------------------------------------------------------------
__global__ __launch_bounds__(256) void gemm_qkv_kernel(
    const unsigned short* __restrict__ A, const unsigned short* __restrict__ Bt,
    const float* __restrict__ cs, const float* __restrict__ sn,
    unsigned short* __restrict__ qb, unsigned short* __restrict__ kb,
    unsigned short* __restrict__ vt) {
  GEMM_PROLOGUE(A, Bt)

  const int col_wave = (int)col0 + wx * 32;     // wave-uniform, within one head
  const int h = col_wave >> 6;
  const int hc = col_wave & 63;                 // 0 or 32 within the head
  const int sb = (int)(row0 & 2047) + wy * 64;  // seq base for this wave
  const int bidx = (int)(row0 >> 11);           // batch (tile never straddles)

  if (h < 20) {
    unsigned short* dst = (h < 16) ? qb : kb;
    const int dstride = (h < 16) ? 1024 : 256;
    const int dcol = (h < 16) ? col_wave : (col_wave - 1024);
    const bool ev = (lrow & 1) == 0;
#pragma unroll
    for (int mi = 0; mi < 4; ++mi) {
#pragma unroll
      for (int ni = 0; ni < 2; ++ni) {
        int ff = (hc + ni * 16 + lrow) >> 1;
#pragma unroll
        for (int r = 0; r < 4; ++r) {
          int s = sb + mi * 16 + quad * 4 + r;
          float v = acc[mi][ni][r];
          float p = __shfl_xor(v, 1);
          float c = cs[s * 32 + ff];
          float si = sn[s * 32 + ff];
          float o = ev ? (v * c - p * si) : (v * c + p * si);
          size_t row = row0 + wy * 64 + mi * 16 + quad * 4 + r;
          dst[row * dstride + dcol + ni * 16 + lrow] = f2bf(o);
        }
      }
    }
  } else {
    const int kvh = h - 20;
    const int g = bidx * KVH + kvh;
#pragma unroll
    for (int mi = 0; mi < 4; ++mi) {
#pragma unroll
      for (int ni = 0; ni < 2; ++ni) {
        int d = hc + ni * 16 + lrow;
        int s0 = sb + mi * 16 + quad * 4;
        ushort4 o;
        o.x = f2bf(acc[mi][ni][0]); o.y = f2bf(acc[mi][ni][1]);
        o.z = f2bf(acc[mi][ni][2]); o.w = f2bf(acc[mi][ni][3]);
        *(ushort4*)&vt[((size_t)(g * 64 + d)) * S + s0] = o;
      }
    }
  }
}

// ---------------------------------------------------------------------------
// Output projection GEMM -> fp32 C. Same 128x64 / BK=128 structure.
// ---------------------------------------------------------------------------
__global__ __launch_bounds__(256) void gemm_bt_kernel(
    const unsigned short* __restrict__ A, const unsigned short* __restrict__ Bt,
    float* __restrict__ C, int N) {
  GEMM_PROLOGUE(A, Bt)

#pragma unroll
  for (int mi = 0; mi < 4; ++mi)
#pragma unroll
    for (int ni = 0; ni < 2; ++ni) {
      size_t col = col0 + wx * 32 + ni * 16 + lrow;
      size_t rowb = row0 + wy * 64 + mi * 16 + quad * 4;
#pragma unroll
      for (int r = 0; r < 4; ++r)
        C[(rowb + r) * N + col] = acc[mi][ni][r];
    }
}

// ---------------------------------------------------------------------------
// MFMA flash attention. One wave per (b, h, 16-query block).
// ---------------------------------------------------------------------------
__global__ __launch_bounds__(256) void attn_kernel(
    const unsigned short* __restrict__ qb,   // [BS][1024]
    const unsigned short* __restrict__ kb,   // [BS][256]
    const unsigned short* __restrict__ vt,   // [B*KVH][64][S]
    unsigned short* __restrict__ ao) {       // [BS][1024]
  __shared__ __align__(16) unsigned short plds[4][16][104];
  const int w = threadIdx.x >> 6, lane = threadIdx.x & 63;
  const int lrow = lane & 15, quad = lane >> 4;
  const int wg = blockIdx.x * 4 + w;
  const int h = wg & (H - 1);
  const int qblk = wg >> 4;
  const int i0 = (qblk & (S / 16 - 1)) * 16;
  const int b = qblk >> 7;
  const int kvh = h >> 2;
  const int jbase = i0 - 80;

  const unsigned short* qrow = qb + (size_t)(b * S + i0 + lrow) * 1024 + h * 64 + quad * 8;
  short8 qf0 = *(const short8*)qrow;
  short8 qf1 = *(const short8*)(qrow + 32);

  floatx4 sc[6];
#pragma unroll
  for (int t = 0; t < 6; ++t) {
    int j = jbase + t * 16 + lrow;
    int jc = j < 0 ? 0 : j;
    const unsigned short* krow = kb + (size_t)(b * S + jc) * 256 + kvh * 64 + quad * 8;
    short8 kf0 = *(const short8*)krow;
    short8 kf1 = *(const short8*)(krow + 32);
    floatx4 a = {0.f, 0.f, 0.f, 0.f};
    a = __builtin_amdgcn_mfma_f32_16x16x32_bf16(qf0, kf0, a, 0, 0, 0);
    a = __builtin_amdgcn_mfma_f32_16x16x32_bf16(qf1, kf1, a, 0, 0, 0);
    sc[t] = a;
  }

  float sv[6][4];
  float mx[4] = {-1e30f, -1e30f, -1e30f, -1e30f};
#pragma unroll
  for (int t = 0; t < 6; ++t) {
    int j = jbase + t * 16 + lrow;
#pragma unroll
    for (int r = 0; r < 4; ++r) {
      int dji = (i0 + quad * 4 + r) - j;
      bool valid = (j >= 0) && (dji >= 0) && (dji <= 64);
      float s = valid ? sc[t][r] * 0.125f : -1e30f;
      sv[t][r] = s;
      mx[r] = fmaxf(mx[r], s);
    }
  }
#pragma unroll
  for (int r = 0; r < 4; ++r)
#pragma unroll
    for (int off = 8; off > 0; off >>= 1)
      mx[r] = fmaxf(mx[r], __shfl_xor(mx[r], off));

  float ls[4] = {0.f, 0.f, 0.f, 0.f};
#pragma unroll
  for (int t = 0; t < 6; ++t)
#pragma unroll
    for (int r = 0; r < 4; ++r) {
      float e = __expf(sv[t][r] - mx[r]);
      sv[t][r] = e;
      ls[r] += e;
    }
#pragma unroll
  for (int r = 0; r < 4; ++r) {
#pragma unroll
    for (int off = 8; off > 0; off >>= 1)
      ls[r] += __shfl_xor(ls[r], off);
    ls[r] = 1.f / ls[r];
  }
#pragma unroll
  for (int t = 0; t < 6; ++t)
#pragma unroll
    for (int r = 0; r < 4; ++r)
      plds[w][quad * 4 + r][t * 16 + lrow] = f2bf(sv[t][r] * ls[r]);
  __syncthreads();

  floatx4 oc[4];
#pragma unroll
  for (int mt = 0; mt < 4; ++mt) oc[mt] = floatx4{0.f, 0.f, 0.f, 0.f};
  const unsigned short* vbase = vt + (size_t)(b * KVH + kvh) * 64 * S;
#pragma unroll
  for (int c = 0; c < 3; ++c) {
    short8 pf = *(const short8*)&plds[w][lrow][c * 32 + quad * 8];
    int j = jbase + c * 32 + quad * 8;
    int jc = j < 0 ? 0 : j;
#pragma unroll
    for (int mt = 0; mt < 4; ++mt) {
      short8 vf = *(const short8*)(vbase + (size_t)(mt * 16 + lrow) * S + jc);
      oc[mt] = __builtin_amdgcn_mfma_f32_16x16x32_bf16(vf, pf, oc[mt], 0, 0, 0);
    }
  }

#pragma unroll
  for (int mt = 0; mt < 4; ++mt) {
    ushort4 o;
    o.x = f2bf(oc[mt][0]); o.y = f2bf(oc[mt][1]);
    o.z = f2bf(oc[mt][2]); o.w = f2bf(oc[mt][3]);
    *(ushort4*)(ao + (size_t)(b * S + i0 + lrow) * 1024 + h * 64 + mt * 16 + quad * 4) = o;
  }
}

// ---------------------------------------------------------------------------
extern "C" void kernel_launch(void* const* d_in, const int* in_sizes, int n_in,
                              void* d_out, int out_size, void* d_ws, size_t ws_size,
                              hipStream_t stream) {
  const float* x  = (const float*)d_in[0];
  const float* fc = (const float*)d_in[1];
  const float* fs = (const float*)d_in[2];
  const float* wq = (const float*)d_in[3];
  const float* wk = (const float*)d_in[4];
  const float* wv = (const float*)d_in[5];
  const float* wo = (const float*)d_in[6];
  float* out = (float*)d_out;

  // ws: [xb 8M][wqkvT 3M][woT 2M][qb 8M][kb 2M][vT 2M][ao 8M] = 33 MiB
  char* base = (char*)d_ws;
  unsigned short* xb    = (unsigned short*)base;
  unsigned short* wqkvT = (unsigned short*)(base + (8u << 20));
  unsigned short* woT   = (unsigned short*)(base + (11u << 20));
  unsigned short* qb    = (unsigned short*)(base + (13u << 20));
  unsigned short* kb    = (unsigned short*)(base + (21u << 20));
  unsigned short* vT    = (unsigned short*)(base + (23u << 20));
  unsigned short* ao    = (unsigned short*)(base + (25u << 20));

  // 1) prep: cast x + transpose all weights
  prep_kernel<<<4096 + 2560, 256, 0, stream>>>(x, wq, wk, wv, wo, xb, wqkvT, woT);

  // 2) fused QKV GEMM + RoPE + V-transpose (grid = rows x cols, XCD-aware)
  gemm_qkv_kernel<<<dim3(BS / 128, QS / 64), 256, 0, stream>>>(
      xb, wqkvT, fc, fs, qb, kb, vT);

  // 3) MFMA attention -> ao bf16 [4096,1024]
  attn_kernel<<<(BS / 16) * H / 4, 256, 0, stream>>>(qb, kb, vT, ao);

  // 4) output projection -> fp32 (grid = rows x cols, XCD-aware)
  gemm_bt_kernel<<<dim3(BS / 128, D / 64), 256, 0, stream>>>(ao, woT, out, D);
}